// Round 6
// baseline (540.103 us; speedup 1.0000x reference)
//
#include <hip/hip_runtime.h>
#include <hip/hip_bf16.h>

#define N_NODES 10000
#define N_EDGES 70000
#define HEADS 6
#define MPAD 10112            // ceil(10000/128)*128
#define SELU_SCALE 1.0507009873554805f
#define SELU_ALPHA  1.6732632423543772f
#define NEG_SLOPE 0.2f

typedef __attribute__((ext_vector_type(8))) __bf16 bf16x8;
typedef __attribute__((ext_vector_type(4))) float f32x4;

__device__ __forceinline__ float selu_f(float x) {
    return x > 0.f ? SELU_SCALE * x : SELU_SCALE * SELU_ALPHA * (__expf(x) - 1.f);
}
__device__ __forceinline__ unsigned short f2bf(float f) {
    __hip_bfloat16 h = __float2bfloat16(f);
    return __builtin_bit_cast(unsigned short, h);
}
__device__ __forceinline__ float bf2f(unsigned short u) {
    unsigned int x = ((unsigned int)u) << 16;
    return __builtin_bit_cast(float, x);
}

// ---------------- CSR build ----------------
__global__ void count_edges_k(const int* __restrict__ dstv, int* __restrict__ counts) {
    int e = blockIdx.x * blockDim.x + threadIdx.x;
    if (e < N_EDGES) atomicAdd(&counts[dstv[e]], 1);
}

__global__ __launch_bounds__(1024) void scan_k(const int* __restrict__ counts, int* __restrict__ offs) {
    __shared__ int part[1024];
    int tid = threadIdx.x;
    const int per = (N_NODES + 1023) / 1024;  // 10
    int start = tid * per;
    int s = 0;
    for (int i = 0; i < per; ++i) { int idx = start + i; if (idx < N_NODES) s += counts[idx]; }
    part[tid] = s;
    __syncthreads();
    for (int off = 1; off < 1024; off <<= 1) {
        int v = (tid >= off) ? part[tid - off] : 0;
        __syncthreads();
        part[tid] += v;
        __syncthreads();
    }
    int run = part[tid] - s;
    for (int i = 0; i < per; ++i) {
        int idx = start + i;
        if (idx < N_NODES) { offs[idx] = run; run += counts[idx]; }
    }
    if (tid == 0) offs[N_NODES] = part[1023];
}

__global__ void fill_csr_k(const int* __restrict__ dstv, const int* __restrict__ offs,
                           int* __restrict__ cursor, int* __restrict__ csr) {
    int e = blockIdx.x * blockDim.x + threadIdx.x;
    if (e < N_EDGES) {
        int d = dstv[e];
        int pos = atomicAdd(&cursor[d], 1);
        csr[offs[d] + pos] = e;
    }
}

// ---------------- input prep ----------------
__global__ void init_coords_k(const float* __restrict__ data, float* __restrict__ coords0,
                              unsigned short* __restrict__ t1) {
    int n = blockIdx.x * blockDim.x + threadIdx.x;
    if (n < N_NODES) {
        float x = data[n * 10 + 0], y = data[n * 10 + 1];
        coords0[2 * n] = x; coords0[2 * n + 1] = y;
        t1[(size_t)n * 256 + 0] = f2bf(x); t1[(size_t)n * 256 + 1] = f2bf(y);
    }
}

__global__ void lin_k(const float* __restrict__ data, const float* __restrict__ W,
                      const float* __restrict__ b, unsigned short* __restrict__ t1) {
    int idx = blockIdx.x * blockDim.x + threadIdx.x;
    if (idx >= N_NODES * 254) return;
    int n = idx / 254, c = idx % 254;
    float acc = b[c];
    const float* dr = data + (size_t)n * 10;
#pragma unroll
    for (int k = 0; k < 10; ++k) acc += dr[k] * W[k * 254 + c];
    t1[(size_t)n * 256 + 2 + c] = f2bf(selu_f(acc));
}

// ---------------- V build: Vt[c][h*K+k] = W[k][h*C+c]  (LDS-tiled transpose) ----------------
__global__ __launch_bounds__(256) void convv_k(const float* __restrict__ W,
                                               unsigned short* __restrict__ Vt,
                                               int K, int C, int K6) {
    __shared__ float tile[64][65];
    const int tx = threadIdx.x;      // 0..63
    const int ty = threadIdx.y;      // 0..3
    const int k0 = blockIdx.x * 64;  // k' tile base
    const int c0 = blockIdx.y * 64;  // c tile base
    for (int i = ty; i < 64; i += 4) {
        int kk = k0 + i;             // k' = h*K + k
        int h = kk / K, k = kk - h * K;
        int c = c0 + tx;
        tile[i][tx] = (c < C) ? W[(size_t)k * (HEADS * C) + h * C + c] : 0.f;
    }
    __syncthreads();
    for (int i = ty; i < 64; i += 4) {
        int c = c0 + i;
        Vt[(size_t)c * K6 + k0 + tx] = f2bf(tile[tx][i]);
    }
}

// ---------------- MFMA GEMM + fused selu epilogue ----------------
// tnext[r][off + c] = selu( (1/6) * thagg[r] . Vt[c] ),  r < N_NODES, c < Cfeat
__global__ __launch_bounds__(256) void gemm_feat_k(
    const unsigned short* __restrict__ A,   // bf16 [MPAD][K]
    const unsigned short* __restrict__ Bt,  // bf16 [Cpad][K]
    unsigned short* __restrict__ outT,      // bf16 [MPAD][ld]
    int K, int ld, int off, int Cfeat) {
    __shared__ unsigned short lds[16384];   // 32 KB: A tile [128][64] + B tile [128][64]
    const int tid = threadIdx.x;
    const int lane = tid & 63, wid = tid >> 6;
    const int wm = wid >> 1, wn = wid & 1;
    const int m0 = blockIdx.y * 128;
    const int n0 = blockIdx.x * 128;

    f32x4 acc[4][4] = {};   // acc[fm][fn]

    const unsigned short* gsrc[8];
    unsigned ldsoff[8];
#pragma unroll
    for (int i = 0; i < 8; ++i) {
        const int half = i >> 2;                    // 0 = A-tile, 1 = B-tile
        const int slot = (i & 3) * 256 + tid;       // 16B slot within tile
        const int r = slot >> 3;                    // tile row (0..127)
        const int c16 = slot & 7;                   // 16B column slot
        const int ksl = c16 ^ (r & 7);              // inverse-swizzled source k-slot
        gsrc[i] = (half ? (Bt + (size_t)(n0 + r) * K) : (A + (size_t)(m0 + r) * K)) + ksl * 8;
        ldsoff[i] = (unsigned)(half * 8192 + ((i & 3) * 256 + wid * 64) * 8);
    }

    for (int kt = 0; kt < K; kt += 64) {
#pragma unroll
        for (int i = 0; i < 8; ++i) {
            __builtin_amdgcn_global_load_lds(
                (const __attribute__((address_space(1))) unsigned int*)(gsrc[i] + kt),
                (__attribute__((address_space(3))) unsigned int*)(&lds[ldsoff[i]]),
                16, 0, 0);
        }
        __syncthreads();
#pragma unroll
        for (int kc = 0; kc < 2; ++kc) {
            const int xo = (((kc * 4 + (lane >> 4)) ^ (lane & 7)) << 4);
            bf16x8 aop[4], bop[4];
#pragma unroll
            for (int f = 0; f < 4; ++f) {
                const int rA = wm * 64 + f * 16 + (lane & 15);
                bop[f] = *(const bf16x8*)((const char*)lds + rA * 128 + xo);
                const int rB = wn * 64 + f * 16 + (lane & 15);
                aop[f] = *(const bf16x8*)((const char*)lds + 16384 * 1 + rB * 128 + xo);
            }
#pragma unroll
            for (int fm = 0; fm < 4; ++fm)
#pragma unroll
                for (int fn = 0; fn < 4; ++fn)
                    acc[fm][fn] = __builtin_amdgcn_mfma_f32_16x16x32_bf16(
                        aop[fn], bop[fm], acc[fm][fn], 0, 0, 0);
        }
        __syncthreads();
    }

    const int mrow = m0 + wm * 64 + (lane & 15);
    const int ncol = n0 + wn * 64 + ((lane >> 4) * 4);
#pragma unroll
    for (int fm = 0; fm < 4; ++fm) {
        int r = mrow + fm * 16;
        if (r >= N_NODES) continue;
#pragma unroll
        for (int fn = 0; fn < 4; ++fn) {
            int cb = ncol + fn * 16;
            f32x4 v = acc[fm][fn];
            float o0 = selu_f(v.x * (1.f / 6.f));
            float o1 = selu_f(v.y * (1.f / 6.f));
            float o2 = selu_f(v.z * (1.f / 6.f));
            float o3 = selu_f(v.w * (1.f / 6.f));
            unsigned short* dst = outT + (size_t)r * ld + off + cb;
            if (cb + 3 < Cfeat) {
                *(unsigned int*)(dst + 0) = (unsigned int)f2bf(o0) | ((unsigned int)f2bf(o1) << 16);
                *(unsigned int*)(dst + 2) = (unsigned int)f2bf(o2) | ((unsigned int)f2bf(o3) << 16);
            } else {
                if (cb + 0 < Cfeat) dst[0] = f2bf(o0);
                if (cb + 1 < Cfeat) dst[1] = f2bf(o1);
                if (cb + 2 < Cfeat) dst[2] = f2bf(o2);
                if (cb + 3 < Cfeat) dst[3] = f2bf(o3);
            }
        }
    }
}

// ---------------- attention ----------------
__global__ __launch_bounds__(64) void fold2_k(const float* __restrict__ W,
                                              const float* __restrict__ avs,
                                              const float* __restrict__ avd,
                                              float* __restrict__ wsf,
                                              float* __restrict__ wdf,
                                              int K, int C) {
    int bid = blockIdx.x;               // k*HEADS + h
    int k = bid / HEADS, h = bid % HEADS;
    int lane = threadIdx.x;
    const float* wr = W + (size_t)k * (HEADS * C) + h * C;
    const float* sr = avs + h * C;
    const float* dr = avd + h * C;
    float s = 0.f, d = 0.f;
    for (int c = lane; c < C; c += 64) {
        float w = wr[c];
        s += w * sr[c];
        d += w * dr[c];
    }
#pragma unroll
    for (int off = 32; off > 0; off >>= 1) {
        s += __shfl_xor(s, off);
        d += __shfl_xor(d, off);
    }
    if (lane == 0) { wsf[bid] = s; wdf[bid] = d; }
}

// One wave per node: vectorized row load, 12 dots, butterfly reduce.
__global__ __launch_bounds__(256) void proj2_k(const unsigned short* __restrict__ t,
                                               const float* __restrict__ wsf,
                                               const float* __restrict__ wdf,
                                               float* __restrict__ a_s,
                                               float* __restrict__ a_d, int K) {
    const int wv = threadIdx.x >> 6;
    const int lane = threadIdx.x & 63;
    const int n = blockIdx.x * 4 + wv;
    if (n >= N_NODES) return;
    const unsigned short* tr = t + (size_t)n * K;
    const int kpl = K >> 6;             // 2, 4, or 8 elems per lane
    const int k0 = lane * kpl;

    unsigned int buf[4] = {0u, 0u, 0u, 0u};
    if (kpl == 8) {
        uint4 u = *(const uint4*)(tr + k0);
        buf[0] = u.x; buf[1] = u.y; buf[2] = u.z; buf[3] = u.w;
    } else if (kpl == 4) {
        uint2 u = *(const uint2*)(tr + k0);
        buf[0] = u.x; buf[1] = u.y;
    } else {
        buf[0] = *(const unsigned int*)(tr + k0);
    }

    float s[HEADS] = {}, d[HEADS] = {};
#pragma unroll
    for (int j = 0; j < 8; ++j) {
        if (j >= kpl) break;
        unsigned int w = buf[j >> 1];
        unsigned short u = (j & 1) ? (unsigned short)(w >> 16) : (unsigned short)(w & 0xffff);
        float v = bf2f(u);
        const float* ws = wsf + (size_t)(k0 + j) * HEADS;
        const float* wd = wdf + (size_t)(k0 + j) * HEADS;
#pragma unroll
        for (int h = 0; h < HEADS; ++h) {
            s[h] += v * ws[h];
            d[h] += v * wd[h];
        }
    }
#pragma unroll
    for (int off = 32; off > 0; off >>= 1) {
#pragma unroll
        for (int h = 0; h < HEADS; ++h) {
            s[h] += __shfl_xor(s[h], off);
            d[h] += __shfl_xor(d[h], off);
        }
    }
    if (lane == 0) {
#pragma unroll
        for (int h = 0; h < HEADS; ++h) {
            a_s[n * HEADS + h] = s[h];
            a_d[n * HEADS + h] = d[h];
        }
    }
}

__global__ void edge_logits_k(const int* __restrict__ srcv, const int* __restrict__ dstv,
                              const float* __restrict__ a_s, const float* __restrict__ a_d,
                              float* __restrict__ earr) {
    int idx = blockIdx.x * blockDim.x + threadIdx.x;
    if (idx >= N_EDGES * HEADS) return;
    int e = idx / HEADS, h = idx % HEADS;
    float v = a_s[srcv[e] * HEADS + h] + a_d[dstv[e] * HEADS + h];
    earr[idx] = v > 0.f ? v : NEG_SLOPE * v;
}

__global__ void softmax_k(const float* __restrict__ earr, const int* __restrict__ csr,
                          const int* __restrict__ offs, float* __restrict__ alpha) {
    int idx = blockIdx.x * blockDim.x + threadIdx.x;
    if (idx >= N_NODES * HEADS) return;
    int n = idx / HEADS, h = idx % HEADS;
    int r0 = offs[n], r1 = offs[n + 1];
    if (r0 == r1) return;
    float m = -1e30f;
    for (int i = r0; i < r1; ++i) m = fmaxf(m, earr[csr[i] * HEADS + h]);
    float denom = 0.f;
    for (int i = r0; i < r1; ++i) {
        float ex = __expf(earr[csr[i] * HEADS + h] - m);
        alpha[csr[i] * HEADS + h] = ex;
        denom += ex;
    }
    float rd = 1.f / denom;
    for (int i = r0; i < r1; ++i) alpha[csr[i] * HEADS + h] *= rd;
}

// ---------------- pre-GEMM aggregation: thagg[n][h*K+k] = sum_e alpha[e][h]*t[src][k] ----------
__global__ __launch_bounds__(256) void aggregate_t_k(
    const unsigned short* __restrict__ t, const float* __restrict__ alpha,
    const int* __restrict__ csr, const int* __restrict__ offs,
    const int* __restrict__ srcv, unsigned short* __restrict__ thagg, int K) {
    const int n = blockIdx.x;
    const int tid = threadIdx.x;
    const int r0 = offs[n], r1 = offs[n + 1];
    const int K6 = K * HEADS;
    if (K == 512) {
        float acc0[HEADS] = {}, acc1[HEADS] = {};
        const int k0 = tid * 2;
        for (int i = r0; i < r1; ++i) {
            int ee = csr[i];
            int s = srcv[ee];
            unsigned int u = *(const unsigned int*)(t + (size_t)s * 512 + k0);
            float v0 = bf2f((unsigned short)(u & 0xffff));
            float v1 = bf2f((unsigned short)(u >> 16));
            const float* al = alpha + (size_t)ee * HEADS;
#pragma unroll
            for (int h = 0; h < HEADS; ++h) {
                float a = al[h];
                acc0[h] += a * v0;
                acc1[h] += a * v1;
            }
        }
#pragma unroll
        for (int h = 0; h < HEADS; ++h) {
            unsigned int pk = (unsigned int)f2bf(acc0[h]) | ((unsigned int)f2bf(acc1[h]) << 16);
            *(unsigned int*)(thagg + (size_t)n * K6 + h * 512 + k0) = pk;
        }
    } else {  // K == 256
        float acc[HEADS] = {};
        for (int i = r0; i < r1; ++i) {
            int ee = csr[i];
            int s = srcv[ee];
            float v = bf2f(t[(size_t)s * 256 + tid]);
            const float* al = alpha + (size_t)ee * HEADS;
#pragma unroll
            for (int h = 0; h < HEADS; ++h) acc[h] += al[h] * v;
        }
#pragma unroll
        for (int h = 0; h < HEADS; ++h)
            thagg[(size_t)n * K6 + h * 256 + tid] = f2bf(acc[h]);
    }
}

__global__ void move_coords_k(const float* __restrict__ cprev, const float* __restrict__ alpha,
                              const int* __restrict__ csr, const int* __restrict__ offs,
                              const int* __restrict__ srcv, const int* __restrict__ bd,
                              float* __restrict__ cout, unsigned short* __restrict__ tnext,
                              int ld, int off) {
    int n = blockIdx.x * blockDim.x + threadIdx.x;
    if (n >= N_NODES) return;
    float cx, cy;
    if (bd[n] != 0) {
        cx = cprev[2 * n]; cy = cprev[2 * n + 1];
    } else {
        cx = 0.f; cy = 0.f;
        int r0 = offs[n], r1 = offs[n + 1];
        for (int i = r0; i < r1; ++i) {
            int ee = csr[i];
            int s = srcv[ee];
            const float* al = alpha + (size_t)ee * HEADS;
            float am = (al[0] + al[1] + al[2] + al[3] + al[4] + al[5]) * (1.f / 6.f);
            cx += am * cprev[2 * s];
            cy += am * cprev[2 * s + 1];
        }
    }
    cout[2 * n] = cx; cout[2 * n + 1] = cy;
    if (tnext) {
        tnext[(size_t)n * ld + off + 0] = f2bf(cx);
        tnext[(size_t)n * ld + off + 1] = f2bf(cy);
    }
}

__global__ void copy2_k(const float* __restrict__ srcc, unsigned short* __restrict__ t,
                        int ld, int off) {
    int n = blockIdx.x * blockDim.x + threadIdx.x;
    if (n < N_NODES) {
        t[(size_t)n * ld + off + 0] = f2bf(srcc[2 * n]);
        t[(size_t)n * ld + off + 1] = f2bf(srcc[2 * n + 1]);
    }
}

static inline int cdiv(int a, int b) { return (a + b - 1) / b; }

extern "C" void kernel_launch(void* const* d_in, const int* in_sizes, int n_in,
                              void* d_out, int out_size, void* d_ws, size_t ws_size,
                              hipStream_t stream) {
    const float* data = (const float*)d_in[0];
    const int* eidx = (const int*)d_in[1];
    const int* bd = (const int*)d_in[2];
    const float* W_lin = (const float*)d_in[4];
    const float* b_lin = (const float*)d_in[5];
    const float* Wl[4]  = {(const float*)d_in[6],  (const float*)d_in[9],
                           (const float*)d_in[12], (const float*)d_in[15]};
    const float* Asrc[4] = {(const float*)d_in[7],  (const float*)d_in[10],
                            (const float*)d_in[13], (const float*)d_in[16]};
    const float* Adst[4] = {(const float*)d_in[8],  (const float*)d_in[11],
                            (const float*)d_in[14], (const float*)d_in[17]};
    const int Kd[4] = {256, 512, 256, 128};
    const int Cd[4] = {508, 250, 120, 20};
    const int Cpadd[4] = {512, 256, 128, 0};   // padded feature-out dim (GEMM N)

    const int* srcv = eidx;
    const int* dstv = eidx + N_EDGES;

    char* p = (char*)d_ws;
    auto alloc = [&](size_t bytes) -> void* {
        void* r = (void*)p;
        p += (bytes + 255) & ~(size_t)255;
        return r;
    };
    unsigned short* tb1 = (unsigned short*)alloc((size_t)MPAD * 256 * 2);
    unsigned short* tb2 = (unsigned short*)alloc((size_t)MPAD * 512 * 2);
    unsigned short* tb3 = (unsigned short*)alloc((size_t)MPAD * 256 * 2);
    unsigned short* tb4 = (unsigned short*)alloc((size_t)MPAD * 128 * 2);
    unsigned short* thagg = (unsigned short*)alloc((size_t)MPAD * 3072 * 2);  // max K6=3072
    unsigned short* Vt  = (unsigned short*)alloc((size_t)512 * 3072 * 2);     // max Cpad*K6
    float* coords0 = (float*)alloc((size_t)N_NODES * 2 * 4);
    float* c1 = (float*)alloc((size_t)N_NODES * 2 * 4);
    float* c2 = (float*)alloc((size_t)N_NODES * 2 * 4);
    float* c3 = (float*)alloc((size_t)N_NODES * 2 * 4);
    float* a_s = (float*)alloc((size_t)N_NODES * HEADS * 4);
    float* a_d = (float*)alloc((size_t)N_NODES * HEADS * 4);
    float* earr = (float*)alloc((size_t)N_EDGES * HEADS * 4);
    float* alpha = (float*)alloc((size_t)N_EDGES * HEADS * 4);
    float* wsf = (float*)alloc((size_t)512 * HEADS * 4);
    float* wdf = (float*)alloc((size_t)512 * HEADS * 4);
    int* counts = (int*)alloc((size_t)N_NODES * 4);
    int* offs = (int*)alloc((size_t)(N_NODES + 1) * 4);
    int* cursor = (int*)alloc((size_t)N_NODES * 4);
    int* csr = (int*)alloc((size_t)N_EDGES * 4);

    hipMemsetAsync(counts, 0, N_NODES * sizeof(int), stream);
    hipMemsetAsync(cursor, 0, N_NODES * sizeof(int), stream);
    count_edges_k<<<cdiv(N_EDGES, 256), 256, 0, stream>>>(dstv, counts);
    scan_k<<<1, 1024, 0, stream>>>(counts, offs);
    fill_csr_k<<<cdiv(N_EDGES, 256), 256, 0, stream>>>(dstv, offs, cursor, csr);

    init_coords_k<<<cdiv(N_NODES, 256), 256, 0, stream>>>(data, coords0, tb1);
    lin_k<<<cdiv(N_NODES * 254, 256), 256, 0, stream>>>(data, W_lin, b_lin, tb1);

    unsigned short* tin[4]   = {tb1, tb2, tb3, tb4};
    unsigned short* tnext[4] = {tb2, tb3, tb4, nullptr};
    int ldn[4]  = {512, 256, 128, 0};
    int foff[4] = {4, 6, 8, 0};
    float* cprev[4] = {coords0, c1, c2, c3};
    float* cout[4]  = {c1, c2, c3, (float*)d_out};

    for (int l = 0; l < 4; ++l) {
        int K = Kd[l], C = Cd[l], Cpad = Cpadd[l];
        int K6 = K * HEADS;
        fold2_k<<<K * HEADS, 64, 0, stream>>>(Wl[l], Asrc[l], Adst[l], wsf, wdf, K, C);
        proj2_k<<<cdiv(N_NODES, 4), 256, 0, stream>>>(tin[l], wsf, wdf, a_s, a_d, K);
        edge_logits_k<<<cdiv(N_EDGES * HEADS, 256), 256, 0, stream>>>(srcv, dstv, a_s, a_d, earr);
        softmax_k<<<cdiv(N_NODES * HEADS, 256), 256, 0, stream>>>(earr, csr, offs, alpha);

        if (l < 3) {
            convv_k<<<dim3(K6 / 64, Cpad / 64), dim3(64, 4), 0, stream>>>(
                Wl[l], Vt, K, C, K6);
            aggregate_t_k<<<N_NODES, 256, 0, stream>>>(
                tin[l], alpha, csr, offs, srcv, thagg, K);
            gemm_feat_k<<<dim3(Cpad / 128, MPAD / 128), 256, 0, stream>>>(
                thagg, Vt, tnext[l], K6, ldn[l], foff[l], C);
        }
        move_coords_k<<<cdiv(N_NODES, 256), 256, 0, stream>>>(
            cprev[l], alpha, csr, offs, srcv, bd, cout[l], tnext[l], ldn[l], 0);
        if (l == 0) {
            copy2_k<<<cdiv(N_NODES, 256), 256, 0, stream>>>(coords0, tb2, 512, 2);
        } else if (l == 1) {
            copy2_k<<<cdiv(N_NODES, 256), 256, 0, stream>>>(c1, tb3, 256, 2);
            copy2_k<<<cdiv(N_NODES, 256), 256, 0, stream>>>(coords0, tb3, 256, 4);
        } else if (l == 2) {
            copy2_k<<<cdiv(N_NODES, 256), 256, 0, stream>>>(c2, tb4, 128, 2);
            copy2_k<<<cdiv(N_NODES, 256), 256, 0, stream>>>(c1, tb4, 128, 4);
            copy2_k<<<cdiv(N_NODES, 256), 256, 0, stream>>>(coords0, tb4, 128, 6);
        }
    }
}

// Round 7
// 518.927 us; speedup vs baseline: 1.0408x; 1.0408x over previous
//
#include <hip/hip_runtime.h>
#include <hip/hip_bf16.h>

#define N_NODES 10000
#define N_EDGES 70000
#define HEADS 6
#define MPAD 10112            // ceil(10000/128)*128
#define SELU_SCALE 1.0507009873554805f
#define SELU_ALPHA  1.6732632423543772f
#define NEG_SLOPE 0.2f

typedef __attribute__((ext_vector_type(8))) __bf16 bf16x8;
typedef __attribute__((ext_vector_type(4))) float f32x4;

__device__ __forceinline__ float selu_f(float x) {
    return x > 0.f ? SELU_SCALE * x : SELU_SCALE * SELU_ALPHA * (__expf(x) - 1.f);
}
__device__ __forceinline__ unsigned short f2bf(float f) {
    __hip_bfloat16 h = __float2bfloat16(f);
    return __builtin_bit_cast(unsigned short, h);
}
__device__ __forceinline__ float bf2f(unsigned short u) {
    unsigned int x = ((unsigned int)u) << 16;
    return __builtin_bit_cast(float, x);
}

// ---------------- CSR build ----------------
__global__ void count_edges_k(const int* __restrict__ dstv, int* __restrict__ counts) {
    int e = blockIdx.x * blockDim.x + threadIdx.x;
    if (e < N_EDGES) atomicAdd(&counts[dstv[e]], 1);
}

__global__ __launch_bounds__(1024) void scan_k(const int* __restrict__ counts, int* __restrict__ offs) {
    __shared__ int part[1024];
    int tid = threadIdx.x;
    const int per = (N_NODES + 1023) / 1024;  // 10
    int start = tid * per;
    int s = 0;
    for (int i = 0; i < per; ++i) { int idx = start + i; if (idx < N_NODES) s += counts[idx]; }
    part[tid] = s;
    __syncthreads();
    for (int off = 1; off < 1024; off <<= 1) {
        int v = (tid >= off) ? part[tid - off] : 0;
        __syncthreads();
        part[tid] += v;
        __syncthreads();
    }
    int run = part[tid] - s;
    for (int i = 0; i < per; ++i) {
        int idx = start + i;
        if (idx < N_NODES) { offs[idx] = run; run += counts[idx]; }
    }
    if (tid == 0) offs[N_NODES] = part[1023];
}

__global__ void fill_csr_k(const int* __restrict__ dstv, const int* __restrict__ offs,
                           int* __restrict__ cursor, int* __restrict__ csr) {
    int e = blockIdx.x * blockDim.x + threadIdx.x;
    if (e < N_EDGES) {
        int d = dstv[e];
        int pos = atomicAdd(&cursor[d], 1);
        csr[offs[d] + pos] = e;
    }
}

// ---------------- input prep ----------------
__global__ void init_coords_k(const float* __restrict__ data, float* __restrict__ coords0,
                              unsigned short* __restrict__ t1) {
    int n = blockIdx.x * blockDim.x + threadIdx.x;
    if (n < N_NODES) {
        float x = data[n * 10 + 0], y = data[n * 10 + 1];
        coords0[2 * n] = x; coords0[2 * n + 1] = y;
        t1[(size_t)n * 256 + 0] = f2bf(x); t1[(size_t)n * 256 + 1] = f2bf(y);
    }
}

__global__ void lin_k(const float* __restrict__ data, const float* __restrict__ W,
                      const float* __restrict__ b, unsigned short* __restrict__ t1) {
    int idx = blockIdx.x * blockDim.x + threadIdx.x;
    if (idx >= N_NODES * 254) return;
    int n = idx / 254, c = idx % 254;
    float acc = b[c];
    const float* dr = data + (size_t)n * 10;
#pragma unroll
    for (int k = 0; k < 10; ++k) acc += dr[k] * W[k * 254 + c];
    t1[(size_t)n * 256 + 2 + c] = f2bf(selu_f(acc));
}

// ---------------- V build: Vt[c][h*K+k] = W[k][h*C+c]  (LDS-tiled transpose) ----------------
__global__ __launch_bounds__(256) void convv_k(const float* __restrict__ W,
                                               unsigned short* __restrict__ Vt,
                                               int K, int C, int K6) {
    __shared__ float tile[64][65];
    const int tx = threadIdx.x;      // 0..63
    const int ty = threadIdx.y;      // 0..3
    const int k0 = blockIdx.x * 64;  // k' tile base
    const int c0 = blockIdx.y * 64;  // c tile base
    for (int i = ty; i < 64; i += 4) {
        int kk = k0 + i;             // k' = h*K + k
        int h = kk / K, k = kk - h * K;
        int c = c0 + tx;
        tile[i][tx] = (c < C) ? W[(size_t)k * (HEADS * C) + h * C + c] : 0.f;
    }
    __syncthreads();
    for (int i = ty; i < 64; i += 4) {
        int c = c0 + i;
        Vt[(size_t)c * K6 + k0 + tx] = f2bf(tile[tx][i]);
    }
}

// ---------------- split-K MFMA GEMM: partial[kz][m][n] (bf16, no epilogue) ----------------
__global__ __launch_bounds__(256) void gemm_split_k(
    const unsigned short* __restrict__ A,   // bf16 [MPAD][Kpitch]
    const unsigned short* __restrict__ Bt,  // bf16 [Npad][Kpitch]
    unsigned short* __restrict__ part,      // bf16 [KS][MPAD][Npad]
    int Kpitch, int klen, int Npad) {
    __shared__ unsigned short lds[16384];   // 32 KB: A tile [128][64] + B tile [128][64]
    const int tid = threadIdx.x;
    const int lane = tid & 63, wid = tid >> 6;
    const int wm = wid >> 1, wn = wid & 1;
    const int m0 = blockIdx.y * 128;
    const int n0 = blockIdx.x * 128;
    const int kz = blockIdx.z;
    const int kbeg = kz * klen;

    f32x4 acc[4][4] = {};   // acc[fm][fn]

    const unsigned short* gsrc[8];
    unsigned ldsoff[8];
#pragma unroll
    for (int i = 0; i < 8; ++i) {
        const int half = i >> 2;                    // 0 = A-tile, 1 = B-tile
        const int slot = (i & 3) * 256 + tid;       // 16B slot within tile
        const int r = slot >> 3;                    // tile row (0..127)
        const int c16 = slot & 7;                   // 16B column slot
        const int ksl = c16 ^ (r & 7);              // inverse-swizzled source k-slot
        gsrc[i] = (half ? (Bt + (size_t)(n0 + r) * Kpitch) : (A + (size_t)(m0 + r) * Kpitch)) + ksl * 8;
        ldsoff[i] = (unsigned)(half * 8192 + ((i & 3) * 256 + wid * 64) * 8);
    }

    for (int kt = kbeg; kt < kbeg + klen; kt += 64) {
#pragma unroll
        for (int i = 0; i < 8; ++i) {
            __builtin_amdgcn_global_load_lds(
                (const __attribute__((address_space(1))) unsigned int*)(gsrc[i] + kt),
                (__attribute__((address_space(3))) unsigned int*)(&lds[ldsoff[i]]),
                16, 0, 0);
        }
        __syncthreads();
#pragma unroll
        for (int kc = 0; kc < 2; ++kc) {
            const int xo = (((kc * 4 + (lane >> 4)) ^ (lane & 7)) << 4);
            bf16x8 aop[4], bop[4];
#pragma unroll
            for (int f = 0; f < 4; ++f) {
                const int rA = wm * 64 + f * 16 + (lane & 15);
                bop[f] = *(const bf16x8*)((const char*)lds + rA * 128 + xo);
                const int rB = wn * 64 + f * 16 + (lane & 15);
                aop[f] = *(const bf16x8*)((const char*)lds + 16384 * 1 + rB * 128 + xo);
            }
#pragma unroll
            for (int fm = 0; fm < 4; ++fm)
#pragma unroll
                for (int fn = 0; fn < 4; ++fn)
                    acc[fm][fn] = __builtin_amdgcn_mfma_f32_16x16x32_bf16(
                        aop[fn], bop[fm], acc[fm][fn], 0, 0, 0);
        }
        __syncthreads();
    }

    unsigned short* pbase = part + (size_t)kz * MPAD * Npad;
    const int mrow = m0 + wm * 64 + (lane & 15);
    const int ncol = n0 + wn * 64 + ((lane >> 4) * 4);
#pragma unroll
    for (int fm = 0; fm < 4; ++fm) {
#pragma unroll
        for (int fn = 0; fn < 4; ++fn) {
            f32x4 v = acc[fm][fn];
            unsigned int u0 = (unsigned int)f2bf(v.x) | ((unsigned int)f2bf(v.y) << 16);
            unsigned int u1 = (unsigned int)f2bf(v.z) | ((unsigned int)f2bf(v.w) << 16);
            uint2 pk = make_uint2(u0, u1);
            *(uint2*)&pbase[(size_t)(mrow + fm * 16) * Npad + ncol + fn * 16] = pk;
        }
    }
}

// ---------------- reduce partials + selu epilogue ----------------
__global__ __launch_bounds__(256) void reduce_feat_k(
    const unsigned short* __restrict__ part, unsigned short* __restrict__ tnext,
    int KS, int Npad, int ld, int off, int Cfeat) {
    int idx = blockIdx.x * 256 + threadIdx.x;
    int half = Npad >> 1;
    int r = idx / half, cp = idx - r * half;
    if (r >= N_NODES) return;
    int cb = cp * 2;
    if (cb >= Cfeat) return;   // Cfeat is even -> pair fully in or out
    const unsigned int* pp = (const unsigned int*)part;
    size_t stride = (size_t)MPAD * half;
    size_t base = (size_t)r * half + cp;
    float s0 = 0.f, s1 = 0.f;
    for (int kz = 0; kz < KS; ++kz) {
        unsigned int u = pp[kz * stride + base];
        s0 += bf2f((unsigned short)(u & 0xffff));
        s1 += bf2f((unsigned short)(u >> 16));
    }
    float o0 = selu_f(s0 * (1.f / 6.f));
    float o1 = selu_f(s1 * (1.f / 6.f));
    *(unsigned int*)&tnext[(size_t)r * ld + off + cb] =
        (unsigned int)f2bf(o0) | ((unsigned int)f2bf(o1) << 16);
}

// ---------------- attention ----------------
__global__ __launch_bounds__(64) void fold2_k(const float* __restrict__ W,
                                              const float* __restrict__ avs,
                                              const float* __restrict__ avd,
                                              float* __restrict__ wsf,
                                              float* __restrict__ wdf,
                                              int K, int C) {
    int bid = blockIdx.x;               // k*HEADS + h
    int k = bid / HEADS, h = bid % HEADS;
    int lane = threadIdx.x;
    const float* wr = W + (size_t)k * (HEADS * C) + h * C;
    const float* sr = avs + h * C;
    const float* dr = avd + h * C;
    float s = 0.f, d = 0.f;
    for (int c = lane; c < C; c += 64) {
        float w = wr[c];
        s += w * sr[c];
        d += w * dr[c];
    }
#pragma unroll
    for (int off = 32; off > 0; off >>= 1) {
        s += __shfl_xor(s, off);
        d += __shfl_xor(d, off);
    }
    if (lane == 0) { wsf[bid] = s; wdf[bid] = d; }
}

// One wave per node: vectorized row load, 12 dots, butterfly reduce.
__global__ __launch_bounds__(256) void proj2_k(const unsigned short* __restrict__ t,
                                               const float* __restrict__ wsf,
                                               const float* __restrict__ wdf,
                                               float* __restrict__ a_s,
                                               float* __restrict__ a_d, int K) {
    const int wv = threadIdx.x >> 6;
    const int lane = threadIdx.x & 63;
    const int n = blockIdx.x * 4 + wv;
    if (n >= N_NODES) return;
    const unsigned short* tr = t + (size_t)n * K;
    const int kpl = K >> 6;             // 2, 4, or 8 elems per lane
    const int k0 = lane * kpl;

    unsigned int buf[4] = {0u, 0u, 0u, 0u};
    if (kpl == 8) {
        uint4 u = *(const uint4*)(tr + k0);
        buf[0] = u.x; buf[1] = u.y; buf[2] = u.z; buf[3] = u.w;
    } else if (kpl == 4) {
        uint2 u = *(const uint2*)(tr + k0);
        buf[0] = u.x; buf[1] = u.y;
    } else {
        buf[0] = *(const unsigned int*)(tr + k0);
    }

    float s[HEADS] = {}, d[HEADS] = {};
#pragma unroll
    for (int j = 0; j < 8; ++j) {
        if (j >= kpl) break;
        unsigned int w = buf[j >> 1];
        unsigned short u = (j & 1) ? (unsigned short)(w >> 16) : (unsigned short)(w & 0xffff);
        float v = bf2f(u);
        const float* ws = wsf + (size_t)(k0 + j) * HEADS;
        const float* wd = wdf + (size_t)(k0 + j) * HEADS;
#pragma unroll
        for (int h = 0; h < HEADS; ++h) {
            s[h] += v * ws[h];
            d[h] += v * wd[h];
        }
    }
#pragma unroll
    for (int off = 32; off > 0; off >>= 1) {
#pragma unroll
        for (int h = 0; h < HEADS; ++h) {
            s[h] += __shfl_xor(s[h], off);
            d[h] += __shfl_xor(d[h], off);
        }
    }
    if (lane == 0) {
#pragma unroll
        for (int h = 0; h < HEADS; ++h) {
            a_s[n * HEADS + h] = s[h];
            a_d[n * HEADS + h] = d[h];
        }
    }
}

// fused edge-logit + segment softmax: alpha[e][h] normalized attention
__global__ void softmax_k(const float* __restrict__ a_s, const float* __restrict__ a_d,
                          const int* __restrict__ srcv, const int* __restrict__ csr,
                          const int* __restrict__ offs, float* __restrict__ alpha) {
    int idx = blockIdx.x * blockDim.x + threadIdx.x;
    if (idx >= N_NODES * HEADS) return;
    int n = idx / HEADS, h = idx % HEADS;
    int r0 = offs[n], r1 = offs[n + 1];
    if (r0 == r1) return;
    float ad = a_d[n * HEADS + h];
    float m = -1e30f;
    for (int i = r0; i < r1; ++i) {
        float v = a_s[srcv[csr[i]] * HEADS + h] + ad;
        v = v > 0.f ? v : NEG_SLOPE * v;
        m = fmaxf(m, v);
    }
    float denom = 0.f;
    for (int i = r0; i < r1; ++i) {
        int ee = csr[i];
        float v = a_s[srcv[ee] * HEADS + h] + ad;
        v = v > 0.f ? v : NEG_SLOPE * v;
        float ex = __expf(v - m);
        alpha[(size_t)ee * HEADS + h] = ex;
        denom += ex;
    }
    float rd = 1.f / denom;
    for (int i = r0; i < r1; ++i) alpha[(size_t)csr[i] * HEADS + h] *= rd;
}

// ---------------- pre-GEMM aggregation: thagg[n][h*K+k] = sum_e alpha[e][h]*t[src][k] ----------
__global__ __launch_bounds__(256) void aggregate_t_k(
    const unsigned short* __restrict__ t, const float* __restrict__ alpha,
    const int* __restrict__ csr, const int* __restrict__ offs,
    const int* __restrict__ srcv, unsigned short* __restrict__ thagg, int K) {
    const int n = blockIdx.x;
    const int tid = threadIdx.x;
    const int r0 = offs[n], r1 = offs[n + 1];
    const int K6 = K * HEADS;
    if (K == 512) {
        float acc0[HEADS] = {}, acc1[HEADS] = {};
        const int k0 = tid * 2;
        for (int i = r0; i < r1; ++i) {
            int ee = csr[i];
            int s = srcv[ee];
            unsigned int u = *(const unsigned int*)(t + (size_t)s * 512 + k0);
            float v0 = bf2f((unsigned short)(u & 0xffff));
            float v1 = bf2f((unsigned short)(u >> 16));
            const float* al = alpha + (size_t)ee * HEADS;
#pragma unroll
            for (int h = 0; h < HEADS; ++h) {
                float a = al[h];
                acc0[h] += a * v0;
                acc1[h] += a * v1;
            }
        }
#pragma unroll
        for (int h = 0; h < HEADS; ++h) {
            unsigned int pk = (unsigned int)f2bf(acc0[h]) | ((unsigned int)f2bf(acc1[h]) << 16);
            *(unsigned int*)(thagg + (size_t)n * K6 + h * 512 + k0) = pk;
        }
    } else {  // K == 256
        float acc[HEADS] = {};
        for (int i = r0; i < r1; ++i) {
            int ee = csr[i];
            int s = srcv[ee];
            float v = bf2f(t[(size_t)s * 256 + tid]);
            const float* al = alpha + (size_t)ee * HEADS;
#pragma unroll
            for (int h = 0; h < HEADS; ++h) acc[h] += al[h] * v;
        }
#pragma unroll
        for (int h = 0; h < HEADS; ++h)
            thagg[(size_t)n * K6 + h * 256 + tid] = f2bf(acc[h]);
    }
}

// move coords + assemble all coord columns of tnext (cols 2.. = coord chain)
__global__ void move_coords_k(const float* __restrict__ cprev, const float* __restrict__ alpha,
                              const int* __restrict__ csr, const int* __restrict__ offs,
                              const int* __restrict__ srcv, const int* __restrict__ bd,
                              float* __restrict__ cout, unsigned short* __restrict__ tnext,
                              int ld,
                              const float* __restrict__ xA, int offA,
                              const float* __restrict__ xB, int offB) {
    int n = blockIdx.x * blockDim.x + threadIdx.x;
    if (n >= N_NODES) return;
    float px = cprev[2 * n], py = cprev[2 * n + 1];
    float cx, cy;
    if (bd[n] != 0) {
        cx = px; cy = py;
    } else {
        cx = 0.f; cy = 0.f;
        int r0 = offs[n], r1 = offs[n + 1];
        for (int i = r0; i < r1; ++i) {
            int ee = csr[i];
            int s = srcv[ee];
            const float* al = alpha + (size_t)ee * HEADS;
            float am = (al[0] + al[1] + al[2] + al[3] + al[4] + al[5]) * (1.f / 6.f);
            cx += am * cprev[2 * s];
            cy += am * cprev[2 * s + 1];
        }
    }
    cout[2 * n] = cx; cout[2 * n + 1] = cy;
    if (tnext) {
        unsigned short* row = tnext + (size_t)n * ld;
        row[0] = f2bf(cx); row[1] = f2bf(cy);
        row[2] = f2bf(px); row[3] = f2bf(py);
        if (xA) { row[offA] = f2bf(xA[2 * n]); row[offA + 1] = f2bf(xA[2 * n + 1]); }
        if (xB) { row[offB] = f2bf(xB[2 * n]); row[offB + 1] = f2bf(xB[2 * n + 1]); }
    }
}

static inline int cdiv(int a, int b) { return (a + b - 1) / b; }

extern "C" void kernel_launch(void* const* d_in, const int* in_sizes, int n_in,
                              void* d_out, int out_size, void* d_ws, size_t ws_size,
                              hipStream_t stream) {
    const float* data = (const float*)d_in[0];
    const int* eidx = (const int*)d_in[1];
    const int* bd = (const int*)d_in[2];
    const float* W_lin = (const float*)d_in[4];
    const float* b_lin = (const float*)d_in[5];
    const float* Wl[4]  = {(const float*)d_in[6],  (const float*)d_in[9],
                           (const float*)d_in[12], (const float*)d_in[15]};
    const float* Asrc[4] = {(const float*)d_in[7],  (const float*)d_in[10],
                            (const float*)d_in[13], (const float*)d_in[16]};
    const float* Adst[4] = {(const float*)d_in[8],  (const float*)d_in[11],
                            (const float*)d_in[14], (const float*)d_in[17]};
    const int Kd[4] = {256, 512, 256, 128};
    const int Cd[4] = {508, 250, 120, 20};
    const int Cpadd[4] = {512, 256, 128, 0};   // padded feature-out dim (GEMM N)
    const int KSd[4] = {4, 8, 8, 0};           // split-K factor

    const int* srcv = eidx;
    const int* dstv = eidx + N_EDGES;

    char* p = (char*)d_ws;
    auto alloc = [&](size_t bytes) -> void* {
        void* r = (void*)p;
        p += (bytes + 255) & ~(size_t)255;
        return r;
    };
    unsigned short* tb1 = (unsigned short*)alloc((size_t)MPAD * 256 * 2);
    unsigned short* tb2 = (unsigned short*)alloc((size_t)MPAD * 512 * 2);
    unsigned short* tb3 = (unsigned short*)alloc((size_t)MPAD * 256 * 2);
    unsigned short* tb4 = (unsigned short*)alloc((size_t)MPAD * 128 * 2);
    unsigned short* thagg = (unsigned short*)alloc((size_t)MPAD * 3072 * 2);  // max K6=3072
    unsigned short* Vt  = (unsigned short*)alloc((size_t)512 * 3072 * 2);     // max Cpad*K6
    unsigned short* partb = (unsigned short*)alloc((size_t)8 * MPAD * 256 * 2); // split-K partials (max 41.4MB)
    float* coords0 = (float*)alloc((size_t)N_NODES * 2 * 4);
    float* c1 = (float*)alloc((size_t)N_NODES * 2 * 4);
    float* c2 = (float*)alloc((size_t)N_NODES * 2 * 4);
    float* c3 = (float*)alloc((size_t)N_NODES * 2 * 4);
    float* a_s = (float*)alloc((size_t)N_NODES * HEADS * 4);
    float* a_d = (float*)alloc((size_t)N_NODES * HEADS * 4);
    float* alpha = (float*)alloc((size_t)N_EDGES * HEADS * 4);
    float* wsf = (float*)alloc((size_t)512 * HEADS * 4);
    float* wdf = (float*)alloc((size_t)512 * HEADS * 4);
    int* counts = (int*)alloc((size_t)N_NODES * 4);
    int* offs = (int*)alloc((size_t)(N_NODES + 1) * 4);
    int* cursor = (int*)alloc((size_t)N_NODES * 4);
    int* csr = (int*)alloc((size_t)N_EDGES * 4);

    hipMemsetAsync(counts, 0, N_NODES * sizeof(int), stream);
    hipMemsetAsync(cursor, 0, N_NODES * sizeof(int), stream);
    count_edges_k<<<cdiv(N_EDGES, 256), 256, 0, stream>>>(dstv, counts);
    scan_k<<<1, 1024, 0, stream>>>(counts, offs);
    fill_csr_k<<<cdiv(N_EDGES, 256), 256, 0, stream>>>(dstv, offs, cursor, csr);

    init_coords_k<<<cdiv(N_NODES, 256), 256, 0, stream>>>(data, coords0, tb1);
    lin_k<<<cdiv(N_NODES * 254, 256), 256, 0, stream>>>(data, W_lin, b_lin, tb1);

    unsigned short* tin[4]   = {tb1, tb2, tb3, tb4};
    unsigned short* tnext[4] = {tb2, tb3, tb4, nullptr};
    int ldn[4]  = {512, 256, 128, 0};
    int foff[4] = {4, 6, 8, 0};
    float* cprev[4] = {coords0, c1, c2, c3};
    float* cout[4]  = {c1, c2, c3, (float*)d_out};
    // extra coord-chain copies into tnext (beyond cols 0-1 new, 2-3 cprev)
    const float* xAv[4] = {nullptr, coords0, c1, nullptr};
    int offAv[4] = {0, 4, 4, 0};
    const float* xBv[4] = {nullptr, nullptr, coords0, nullptr};
    int offBv[4] = {0, 0, 6, 0};

    for (int l = 0; l < 4; ++l) {
        int K = Kd[l], C = Cd[l], Cpad = Cpadd[l], KS = KSd[l];
        int K6 = K * HEADS;
        fold2_k<<<K * HEADS, 64, 0, stream>>>(Wl[l], Asrc[l], Adst[l], wsf, wdf, K, C);
        proj2_k<<<cdiv(N_NODES, 4), 256, 0, stream>>>(tin[l], wsf, wdf, a_s, a_d, K);
        softmax_k<<<cdiv(N_NODES * HEADS, 256), 256, 0, stream>>>(a_s, a_d, srcv, csr, offs, alpha);

        if (l < 3) {
            convv_k<<<dim3(K6 / 64, Cpad / 64), dim3(64, 4), 0, stream>>>(
                Wl[l], Vt, K, C, K6);
            aggregate_t_k<<<N_NODES, 256, 0, stream>>>(
                tin[l], alpha, csr, offs, srcv, thagg, K);
            int klen = K6 / KS;
            gemm_split_k<<<dim3(Cpad / 128, MPAD / 128, KS), 256, 0, stream>>>(
                thagg, Vt, partb, K6, klen, Cpad);
            reduce_feat_k<<<cdiv(MPAD * (Cpad / 2), 256), 256, 0, stream>>>(
                partb, tnext[l], KS, Cpad, ldn[l], foff[l], C);
        }
        move_coords_k<<<cdiv(N_NODES, 256), 256, 0, stream>>>(
            cprev[l], alpha, csr, offs, srcv, bd, cout[l], tnext[l], ldn[l],
            xAv[l], offAv[l], xBv[l], offBv[l]);
    }
}

// Round 8
// 422.408 us; speedup vs baseline: 1.2786x; 1.2285x over previous
//
#include <hip/hip_runtime.h>
#include <hip/hip_bf16.h>

#define N_NODES 10000
#define N_EDGES 70000
#define HEADS 6
#define MPAD 10112            // ceil(10000/128)*128
#define SELU_SCALE 1.0507009873554805f
#define SELU_ALPHA  1.6732632423543772f
#define NEG_SLOPE 0.2f

typedef __attribute__((ext_vector_type(8))) __bf16 bf16x8;
typedef __attribute__((ext_vector_type(4))) float f32x4;

__device__ __forceinline__ float selu_f(float x) {
    return x > 0.f ? SELU_SCALE * x : SELU_SCALE * SELU_ALPHA * (__expf(x) - 1.f);
}
__device__ __forceinline__ unsigned short f2bf(float f) {
    __hip_bfloat16 h = __float2bfloat16(f);
    return __builtin_bit_cast(unsigned short, h);
}
__device__ __forceinline__ float bf2f(unsigned short u) {
    unsigned int x = ((unsigned int)u) << 16;
    return __builtin_bit_cast(float, x);
}

// ---------------- CSR build ----------------
__global__ void count_edges_k(const int* __restrict__ dstv, int* __restrict__ counts) {
    int e = blockIdx.x * blockDim.x + threadIdx.x;
    if (e < N_EDGES) atomicAdd(&counts[dstv[e]], 1);
}

__global__ __launch_bounds__(1024) void scan_k(const int* __restrict__ counts, int* __restrict__ offs) {
    __shared__ int part[1024];
    int tid = threadIdx.x;
    const int per = (N_NODES + 1023) / 1024;  // 10
    int start = tid * per;
    int s = 0;
    for (int i = 0; i < per; ++i) { int idx = start + i; if (idx < N_NODES) s += counts[idx]; }
    part[tid] = s;
    __syncthreads();
    for (int off = 1; off < 1024; off <<= 1) {
        int v = (tid >= off) ? part[tid - off] : 0;
        __syncthreads();
        part[tid] += v;
        __syncthreads();
    }
    int run = part[tid] - s;
    for (int i = 0; i < per; ++i) {
        int idx = start + i;
        if (idx < N_NODES) { offs[idx] = run; run += counts[idx]; }
    }
    if (tid == 0) offs[N_NODES] = part[1023];
}

__global__ void fill_csr_k(const int* __restrict__ dstv, const int* __restrict__ offs,
                           int* __restrict__ cursor, int* __restrict__ csr) {
    int e = blockIdx.x * blockDim.x + threadIdx.x;
    if (e < N_EDGES) {
        int d = dstv[e];
        int pos = atomicAdd(&cursor[d], 1);
        csr[offs[d] + pos] = e;
    }
}

// ---------------- input prep ----------------
__global__ void init_coords_k(const float* __restrict__ data, float* __restrict__ coords0,
                              unsigned short* __restrict__ t1) {
    int n = blockIdx.x * blockDim.x + threadIdx.x;
    if (n < N_NODES) {
        float x = data[n * 10 + 0], y = data[n * 10 + 1];
        coords0[2 * n] = x; coords0[2 * n + 1] = y;
        t1[(size_t)n * 256 + 0] = f2bf(x); t1[(size_t)n * 256 + 1] = f2bf(y);
    }
}

__global__ void lin_k(const float* __restrict__ data, const float* __restrict__ W,
                      const float* __restrict__ b, unsigned short* __restrict__ t1) {
    int idx = blockIdx.x * blockDim.x + threadIdx.x;
    if (idx >= N_NODES * 254) return;
    int n = idx / 254, c = idx % 254;
    float acc = b[c];
    const float* dr = data + (size_t)n * 10;
#pragma unroll
    for (int k = 0; k < 10; ++k) acc += dr[k] * W[k * 254 + c];
    t1[(size_t)n * 256 + 2 + c] = f2bf(selu_f(acc));
}

// ---------------- V build: Vt[c][h*K+k] = W[k][h*C+c]  (LDS-tiled transpose) ----------------
__global__ __launch_bounds__(256) void convv_k(const float* __restrict__ W,
                                               unsigned short* __restrict__ Vt,
                                               int K, int C, int K6) {
    __shared__ float tile[64][65];
    const int tx = threadIdx.x;      // 0..63
    const int ty = threadIdx.y;      // 0..3
    const int k0 = blockIdx.x * 64;  // k' tile base
    const int c0 = blockIdx.y * 64;  // c tile base
    for (int i = ty; i < 64; i += 4) {
        int kk = k0 + i;             // k' = h*K + k
        int h = kk / K, k = kk - h * K;
        int c = c0 + tx;
        tile[i][tx] = (c < C) ? W[(size_t)k * (HEADS * C) + h * C + c] : 0.f;
    }
    __syncthreads();
    for (int i = ty; i < 64; i += 4) {
        int c = c0 + i;
        Vt[(size_t)c * K6 + k0 + tx] = f2bf(tile[tx][i]);
    }
}

// ---------------- split-K MFMA GEMM: partial[kz][m][n] (bf16, no epilogue) ----------------
__global__ __launch_bounds__(256) void gemm_split_k(
    const unsigned short* __restrict__ A,   // bf16 [MPAD][Kpitch]
    const unsigned short* __restrict__ Bt,  // bf16 [Npad][Kpitch]
    unsigned short* __restrict__ part,      // bf16 [KS][MPAD][Npad]
    int Kpitch, int klen, int Npad) {
    __shared__ unsigned short lds[16384];   // 32 KB: A tile [128][64] + B tile [128][64]
    const int tid = threadIdx.x;
    const int lane = tid & 63, wid = tid >> 6;
    const int wm = wid >> 1, wn = wid & 1;
    const int m0 = blockIdx.y * 128;
    const int n0 = blockIdx.x * 128;
    const int kz = blockIdx.z;
    const int kbeg = kz * klen;

    f32x4 acc[4][4] = {};   // acc[fm][fn]

    const unsigned short* gsrc[8];
    unsigned ldsoff[8];
#pragma unroll
    for (int i = 0; i < 8; ++i) {
        const int half = i >> 2;                    // 0 = A-tile, 1 = B-tile
        const int slot = (i & 3) * 256 + tid;       // 16B slot within tile
        const int r = slot >> 3;                    // tile row (0..127)
        const int c16 = slot & 7;                   // 16B column slot
        const int ksl = c16 ^ (r & 7);              // inverse-swizzled source k-slot
        gsrc[i] = (half ? (Bt + (size_t)(n0 + r) * Kpitch) : (A + (size_t)(m0 + r) * Kpitch)) + ksl * 8;
        ldsoff[i] = (unsigned)(half * 8192 + ((i & 3) * 256 + wid * 64) * 8);
    }

    for (int kt = kbeg; kt < kbeg + klen; kt += 64) {
#pragma unroll
        for (int i = 0; i < 8; ++i) {
            __builtin_amdgcn_global_load_lds(
                (const __attribute__((address_space(1))) unsigned int*)(gsrc[i] + kt),
                (__attribute__((address_space(3))) unsigned int*)(&lds[ldsoff[i]]),
                16, 0, 0);
        }
        __syncthreads();
#pragma unroll
        for (int kc = 0; kc < 2; ++kc) {
            const int xo = (((kc * 4 + (lane >> 4)) ^ (lane & 7)) << 4);
            bf16x8 aop[4], bop[4];
#pragma unroll
            for (int f = 0; f < 4; ++f) {
                const int rA = wm * 64 + f * 16 + (lane & 15);
                bop[f] = *(const bf16x8*)((const char*)lds + rA * 128 + xo);
                const int rB = wn * 64 + f * 16 + (lane & 15);
                aop[f] = *(const bf16x8*)((const char*)lds + 16384 * 1 + rB * 128 + xo);
            }
#pragma unroll
            for (int fm = 0; fm < 4; ++fm)
#pragma unroll
                for (int fn = 0; fn < 4; ++fn)
                    acc[fm][fn] = __builtin_amdgcn_mfma_f32_16x16x32_bf16(
                        aop[fn], bop[fm], acc[fm][fn], 0, 0, 0);
        }
        __syncthreads();
    }

    unsigned short* pbase = part + (size_t)kz * MPAD * Npad;
    const int mrow = m0 + wm * 64 + (lane & 15);
    const int ncol = n0 + wn * 64 + ((lane >> 4) * 4);
#pragma unroll
    for (int fm = 0; fm < 4; ++fm) {
#pragma unroll
        for (int fn = 0; fn < 4; ++fn) {
            f32x4 v = acc[fm][fn];
            unsigned int u0 = (unsigned int)f2bf(v.x) | ((unsigned int)f2bf(v.y) << 16);
            unsigned int u1 = (unsigned int)f2bf(v.z) | ((unsigned int)f2bf(v.w) << 16);
            uint2 pk = make_uint2(u0, u1);
            *(uint2*)&pbase[(size_t)(mrow + fm * 16) * Npad + ncol + fn * 16] = pk;
        }
    }
}

// ---------------- reduce partials + selu epilogue ----------------
__global__ __launch_bounds__(256) void reduce_feat_k(
    const unsigned short* __restrict__ part, unsigned short* __restrict__ tnext,
    int KS, int Npad, int ld, int off, int Cfeat) {
    int idx = blockIdx.x * 256 + threadIdx.x;
    int half = Npad >> 1;
    int r = idx / half, cp = idx - r * half;
    if (r >= N_NODES) return;
    int cb = cp * 2;
    if (cb >= Cfeat) return;   // Cfeat is even -> pair fully in or out
    const unsigned int* pp = (const unsigned int*)part;
    size_t stride = (size_t)MPAD * half;
    size_t base = (size_t)r * half + cp;
    float s0 = 0.f, s1 = 0.f;
    for (int kz = 0; kz < KS; ++kz) {
        unsigned int u = pp[kz * stride + base];
        s0 += bf2f((unsigned short)(u & 0xffff));
        s1 += bf2f((unsigned short)(u >> 16));
    }
    float o0 = selu_f(s0 * (1.f / 6.f));
    float o1 = selu_f(s1 * (1.f / 6.f));
    *(unsigned int*)&tnext[(size_t)r * ld + off + cb] =
        (unsigned int)f2bf(o0) | ((unsigned int)f2bf(o1) << 16);
}

// ---------------- attention ----------------
__global__ __launch_bounds__(64) void fold2_k(const float* __restrict__ W,
                                              const float* __restrict__ avs,
                                              const float* __restrict__ avd,
                                              float* __restrict__ wsf,
                                              float* __restrict__ wdf,
                                              int K, int C) {
    int bid = blockIdx.x;               // k*HEADS + h
    int k = bid / HEADS, h = bid % HEADS;
    int lane = threadIdx.x;
    const float* wr = W + (size_t)k * (HEADS * C) + h * C;
    const float* sr = avs + h * C;
    const float* dr = avd + h * C;
    float s = 0.f, d = 0.f;
    for (int c = lane; c < C; c += 64) {
        float w = wr[c];
        s += w * sr[c];
        d += w * dr[c];
    }
#pragma unroll
    for (int off = 32; off > 0; off >>= 1) {
        s += __shfl_xor(s, off);
        d += __shfl_xor(d, off);
    }
    if (lane == 0) { wsf[bid] = s; wdf[bid] = d; }
}

// One wave per node: vectorized row load, 12 dots, butterfly reduce.
__global__ __launch_bounds__(256) void proj2_k(const unsigned short* __restrict__ t,
                                               const float* __restrict__ wsf,
                                               const float* __restrict__ wdf,
                                               float* __restrict__ a_s,
                                               float* __restrict__ a_d, int K) {
    const int wv = threadIdx.x >> 6;
    const int lane = threadIdx.x & 63;
    const int n = blockIdx.x * 4 + wv;
    if (n >= N_NODES) return;
    const unsigned short* tr = t + (size_t)n * K;
    const int kpl = K >> 6;             // 2, 4, or 8 elems per lane
    const int k0 = lane * kpl;

    unsigned int buf[4] = {0u, 0u, 0u, 0u};
    if (kpl == 8) {
        uint4 u = *(const uint4*)(tr + k0);
        buf[0] = u.x; buf[1] = u.y; buf[2] = u.z; buf[3] = u.w;
    } else if (kpl == 4) {
        uint2 u = *(const uint2*)(tr + k0);
        buf[0] = u.x; buf[1] = u.y;
    } else {
        buf[0] = *(const unsigned int*)(tr + k0);
    }

    float s[HEADS] = {}, d[HEADS] = {};
#pragma unroll
    for (int j = 0; j < 8; ++j) {
        if (j >= kpl) break;
        unsigned int w = buf[j >> 1];
        unsigned short u = (j & 1) ? (unsigned short)(w >> 16) : (unsigned short)(w & 0xffff);
        float v = bf2f(u);
        const float* ws = wsf + (size_t)(k0 + j) * HEADS;
        const float* wd = wdf + (size_t)(k0 + j) * HEADS;
#pragma unroll
        for (int h = 0; h < HEADS; ++h) {
            s[h] += v * ws[h];
            d[h] += v * wd[h];
        }
    }
#pragma unroll
    for (int off = 32; off > 0; off >>= 1) {
#pragma unroll
        for (int h = 0; h < HEADS; ++h) {
            s[h] += __shfl_xor(s[h], off);
            d[h] += __shfl_xor(d[h], off);
        }
    }
    if (lane == 0) {
#pragma unroll
        for (int h = 0; h < HEADS; ++h) {
            a_s[n * HEADS + h] = s[h];
            a_d[n * HEADS + h] = d[h];
        }
    }
}

// ---------------- fused softmax + aggregate + move_coords (block per dst node) -------------
// Phase A: per-head online softmax stats (m, denom) over incoming edges.
// Phase B: alpha into LDS (chunks of 128 edges); k-column threads aggregate t[src];
//          wave 3 accumulates coord centroid.
// Phase C: write thagg row, coords, tnext coord columns.
__global__ __launch_bounds__(256) void attn_agg_move_k(
    const float* __restrict__ a_s, const float* __restrict__ a_d,
    const int* __restrict__ srcv, const int* __restrict__ csr,
    const int* __restrict__ offs,
    const unsigned short* __restrict__ t_in, unsigned short* __restrict__ thagg,
    int K,                                    // 512 / 256 agg width; 0 = no aggregation
    const float* __restrict__ cprev, const int* __restrict__ bd,
    float* __restrict__ cout, unsigned short* __restrict__ tnext, int ld,
    const float* __restrict__ xA, int offA,
    const float* __restrict__ xB, int offB) {
    const int n = blockIdx.x;
    const int tid = threadIdx.x;
    const int lane = tid & 63, w = tid >> 6;
    const int r0 = offs[n], r1 = offs[n + 1];

    __shared__ float m_sh[HEADS], rd_sh[HEADS], ad_sh[HEADS];
    __shared__ float al_sh[128][HEADS];
    __shared__ float cxy_sh[2];

    // ---- phase A ----
    for (int h = w; h < HEADS; h += 4) {
        float ad = a_d[n * HEADS + h];
        if (lane == 0) ad_sh[h] = ad;
        float m = -1e30f, s = 0.f;
        for (int i = r0 + lane; i < r1; i += 64) {
            float v = a_s[srcv[csr[i]] * HEADS + h] + ad;
            v = v > 0.f ? v : NEG_SLOPE * v;
            float nm = fmaxf(m, v);
            s = s * __expf(m - nm) + __expf(v - nm);
            m = nm;
        }
#pragma unroll
        for (int off = 32; off > 0; off >>= 1) {
            float mo = __shfl_xor(m, off);
            float so = __shfl_xor(s, off);
            float nm = fmaxf(m, mo);
            s = s * __expf(m - nm) + so * __expf(mo - nm);
            m = nm;
        }
        if (lane == 0) { m_sh[h] = m; rd_sh[h] = (s > 0.f) ? 1.f / s : 0.f; }
    }
    __syncthreads();

    // ---- phase B (chunked) ----
    float acc0[HEADS] = {}, acc1[HEADS] = {};
    float cx = 0.f, cy = 0.f;
    const int k0 = tid * 2;
    for (int base = r0; base < r1; base += 128) {
        int cnt = min(128, r1 - base);
        for (int j = tid; j < cnt * HEADS; j += 256) {
            int i = j / HEADS, h = j - i * HEADS;
            float v = a_s[srcv[csr[base + i]] * HEADS + h] + ad_sh[h];
            v = v > 0.f ? v : NEG_SLOPE * v;
            al_sh[i][h] = __expf(v - m_sh[h]) * rd_sh[h];
        }
        __syncthreads();
        if (K == 512) {
            for (int i = 0; i < cnt; ++i) {
                int s = srcv[csr[base + i]];
                unsigned int u = *(const unsigned int*)(t_in + (size_t)s * 512 + k0);
                float v0 = bf2f((unsigned short)(u & 0xffff));
                float v1 = bf2f((unsigned short)(u >> 16));
#pragma unroll
                for (int h = 0; h < HEADS; ++h) {
                    float a = al_sh[i][h];
                    acc0[h] += a * v0;
                    acc1[h] += a * v1;
                }
            }
        } else if (K == 256) {
            for (int i = 0; i < cnt; ++i) {
                int s = srcv[csr[base + i]];
                float v = bf2f(t_in[(size_t)s * 256 + tid]);
#pragma unroll
                for (int h = 0; h < HEADS; ++h) acc0[h] += al_sh[i][h] * v;
            }
        }
        if (w == 3) {
            for (int i = lane; i < cnt; i += 64) {
                int s = srcv[csr[base + i]];
                const float* al = al_sh[i];
                float am = (al[0] + al[1] + al[2] + al[3] + al[4] + al[5]) * (1.f / 6.f);
                cx += am * cprev[2 * s];
                cy += am * cprev[2 * s + 1];
            }
        }
        __syncthreads();
    }

    // ---- phase C ----
    if (K == 512) {
#pragma unroll
        for (int h = 0; h < HEADS; ++h) {
            unsigned int pk = (unsigned int)f2bf(acc0[h]) | ((unsigned int)f2bf(acc1[h]) << 16);
            *(unsigned int*)(thagg + (size_t)n * 3072 + h * 512 + k0) = pk;
        }
    } else if (K == 256) {
#pragma unroll
        for (int h = 0; h < HEADS; ++h)
            thagg[(size_t)n * 1536 + h * 256 + tid] = f2bf(acc0[h]);
    }
    if (w == 3) {
#pragma unroll
        for (int off = 32; off > 0; off >>= 1) {
            cx += __shfl_xor(cx, off);
            cy += __shfl_xor(cy, off);
        }
        if (lane == 0) { cxy_sh[0] = cx; cxy_sh[1] = cy; }
    }
    __syncthreads();
    if (tid == 0) {
        float px = cprev[2 * n], py = cprev[2 * n + 1];
        float ocx, ocy;
        if (bd[n] != 0) { ocx = px; ocy = py; }
        else { ocx = cxy_sh[0]; ocy = cxy_sh[1]; }
        cout[2 * n] = ocx; cout[2 * n + 1] = ocy;
        if (tnext) {
            unsigned short* row = tnext + (size_t)n * ld;
            row[0] = f2bf(ocx); row[1] = f2bf(ocy);
            row[2] = f2bf(px);  row[3] = f2bf(py);
            if (xA) { row[offA] = f2bf(xA[2 * n]); row[offA + 1] = f2bf(xA[2 * n + 1]); }
            if (xB) { row[offB] = f2bf(xB[2 * n]); row[offB + 1] = f2bf(xB[2 * n + 1]); }
        }
    }
}

static inline int cdiv(int a, int b) { return (a + b - 1) / b; }

extern "C" void kernel_launch(void* const* d_in, const int* in_sizes, int n_in,
                              void* d_out, int out_size, void* d_ws, size_t ws_size,
                              hipStream_t stream) {
    const float* data = (const float*)d_in[0];
    const int* eidx = (const int*)d_in[1];
    const int* bd = (const int*)d_in[2];
    const float* W_lin = (const float*)d_in[4];
    const float* b_lin = (const float*)d_in[5];
    const float* Wl[4]  = {(const float*)d_in[6],  (const float*)d_in[9],
                           (const float*)d_in[12], (const float*)d_in[15]};
    const float* Asrc[4] = {(const float*)d_in[7],  (const float*)d_in[10],
                            (const float*)d_in[13], (const float*)d_in[16]};
    const float* Adst[4] = {(const float*)d_in[8],  (const float*)d_in[11],
                            (const float*)d_in[14], (const float*)d_in[17]};
    const int Kd[4] = {256, 512, 256, 128};
    const int Cd[4] = {508, 250, 120, 20};
    const int Cpadd[4] = {512, 256, 128, 0};   // padded feature-out dim (GEMM N)
    const int KSd[4] = {2, 4, 4, 0};           // split-K factor (klen = K6/KS = 768/768/384)

    const int* srcv = eidx;
    const int* dstv = eidx + N_EDGES;

    char* p = (char*)d_ws;
    auto alloc = [&](size_t bytes) -> void* {
        void* r = (void*)p;
        p += (bytes + 255) & ~(size_t)255;
        return r;
    };
    unsigned short* tb1 = (unsigned short*)alloc((size_t)MPAD * 256 * 2);
    unsigned short* tb2 = (unsigned short*)alloc((size_t)MPAD * 512 * 2);
    unsigned short* tb3 = (unsigned short*)alloc((size_t)MPAD * 256 * 2);
    unsigned short* tb4 = (unsigned short*)alloc((size_t)MPAD * 128 * 2);
    unsigned short* thagg = (unsigned short*)alloc((size_t)MPAD * 3072 * 2);  // max K6=3072
    unsigned short* Vt  = (unsigned short*)alloc((size_t)512 * 3072 * 2);     // max Cpad*K6
    unsigned short* partb = (unsigned short*)alloc((size_t)8 * MPAD * 256 * 2); // split-K partials
    float* coords0 = (float*)alloc((size_t)N_NODES * 2 * 4);
    float* c1 = (float*)alloc((size_t)N_NODES * 2 * 4);
    float* c2 = (float*)alloc((size_t)N_NODES * 2 * 4);
    float* c3 = (float*)alloc((size_t)N_NODES * 2 * 4);
    float* a_s = (float*)alloc((size_t)N_NODES * HEADS * 4);
    float* a_d = (float*)alloc((size_t)N_NODES * HEADS * 4);
    float* wsf = (float*)alloc((size_t)512 * HEADS * 4);
    float* wdf = (float*)alloc((size_t)512 * HEADS * 4);
    int* counts = (int*)alloc((size_t)N_NODES * 4);
    int* offs = (int*)alloc((size_t)(N_NODES + 1) * 4);
    int* cursor = (int*)alloc((size_t)N_NODES * 4);
    int* csr = (int*)alloc((size_t)N_EDGES * 4);

    hipMemsetAsync(counts, 0, N_NODES * sizeof(int), stream);
    hipMemsetAsync(cursor, 0, N_NODES * sizeof(int), stream);
    count_edges_k<<<cdiv(N_EDGES, 256), 256, 0, stream>>>(dstv, counts);
    scan_k<<<1, 1024, 0, stream>>>(counts, offs);
    fill_csr_k<<<cdiv(N_EDGES, 256), 256, 0, stream>>>(dstv, offs, cursor, csr);

    init_coords_k<<<cdiv(N_NODES, 256), 256, 0, stream>>>(data, coords0, tb1);
    lin_k<<<cdiv(N_NODES * 254, 256), 256, 0, stream>>>(data, W_lin, b_lin, tb1);

    unsigned short* tin[4]   = {tb1, tb2, tb3, tb4};
    unsigned short* tnext[4] = {tb2, tb3, tb4, nullptr};
    int ldn[4]  = {512, 256, 128, 0};
    int foff[4] = {4, 6, 8, 0};
    float* cprev[4] = {coords0, c1, c2, c3};
    float* cout[4]  = {c1, c2, c3, (float*)d_out};
    // extra coord-chain copies into tnext (beyond cols 0-1 new, 2-3 cprev)
    const float* xAv[4] = {nullptr, coords0, c1, nullptr};
    int offAv[4] = {0, 4, 4, 0};
    const float* xBv[4] = {nullptr, nullptr, coords0, nullptr};
    int offBv[4] = {0, 0, 6, 0};

    for (int l = 0; l < 4; ++l) {
        int K = Kd[l], C = Cd[l], Cpad = Cpadd[l], KS = KSd[l];
        int K6 = K * HEADS;
        fold2_k<<<K * HEADS, 64, 0, stream>>>(Wl[l], Asrc[l], Adst[l], wsf, wdf, K, C);
        proj2_k<<<cdiv(N_NODES, 4), 256, 0, stream>>>(tin[l], wsf, wdf, a_s, a_d, K);

        attn_agg_move_k<<<N_NODES, 256, 0, stream>>>(
            a_s, a_d, srcv, csr, offs,
            tin[l], (l < 3) ? thagg : nullptr, (l < 3) ? K : 0,
            cprev[l], bd, cout[l], tnext[l], ldn[l],
            xAv[l], offAv[l], xBv[l], offBv[l]);

        if (l < 3) {
            convv_k<<<dim3(K6 / 64, Cpad / 64), dim3(64, 4), 0, stream>>>(
                Wl[l], Vt, K, C, K6);
            int klen = K6 / KS;
            gemm_split_k<<<dim3(Cpad / 128, MPAD / 128, KS), 256, 0, stream>>>(
                thagg, Vt, partb, K6, klen, Cpad);
            reduce_feat_k<<<cdiv(MPAD * (Cpad / 2), 256), 256, 0, stream>>>(
                partb, tnext[l], KS, Cpad, ldn[l], foff[l], C);
        }
    }
}

// Round 9
// 372.320 us; speedup vs baseline: 1.4506x; 1.1345x over previous
//
#include <hip/hip_runtime.h>
#include <hip/hip_bf16.h>

#define N_NODES 10000
#define N_EDGES 70000
#define HEADS 6
#define MPAD 10112            // ceil(10000/128)*128
#define SELU_SCALE 1.0507009873554805f
#define SELU_ALPHA  1.6732632423543772f
#define NEG_SLOPE 0.2f

typedef __attribute__((ext_vector_type(8))) __bf16 bf16x8;
typedef __attribute__((ext_vector_type(4))) float f32x4;

__device__ __forceinline__ float selu_f(float x) {
    return x > 0.f ? SELU_SCALE * x : SELU_SCALE * SELU_ALPHA * (__expf(x) - 1.f);
}
__device__ __forceinline__ unsigned short f2bf(float f) {
    __hip_bfloat16 h = __float2bfloat16(f);
    return __builtin_bit_cast(unsigned short, h);
}
__device__ __forceinline__ float bf2f(unsigned short u) {
    unsigned int x = ((unsigned int)u) << 16;
    return __builtin_bit_cast(float, x);
}

// ---------------- CSR build ----------------
__global__ void count_edges_k(const int* __restrict__ dstv, int* __restrict__ counts) {
    int e = blockIdx.x * blockDim.x + threadIdx.x;
    if (e < N_EDGES) atomicAdd(&counts[dstv[e]], 1);
}

__global__ __launch_bounds__(1024) void scan_k(const int* __restrict__ counts, int* __restrict__ offs) {
    __shared__ int part[1024];
    int tid = threadIdx.x;
    const int per = (N_NODES + 1023) / 1024;  // 10
    int start = tid * per;
    int s = 0;
    for (int i = 0; i < per; ++i) { int idx = start + i; if (idx < N_NODES) s += counts[idx]; }
    part[tid] = s;
    __syncthreads();
    for (int off = 1; off < 1024; off <<= 1) {
        int v = (tid >= off) ? part[tid - off] : 0;
        __syncthreads();
        part[tid] += v;
        __syncthreads();
    }
    int run = part[tid] - s;
    for (int i = 0; i < per; ++i) {
        int idx = start + i;
        if (idx < N_NODES) { offs[idx] = run; run += counts[idx]; }
    }
    if (tid == 0) offs[N_NODES] = part[1023];
}

__global__ void fill_csr_k(const int* __restrict__ dstv, const int* __restrict__ offs,
                           int* __restrict__ cursor, int* __restrict__ csr) {
    int e = blockIdx.x * blockDim.x + threadIdx.x;
    if (e < N_EDGES) {
        int d = dstv[e];
        int pos = atomicAdd(&cursor[d], 1);
        csr[offs[d] + pos] = e;
    }
}

// ---------------- prep: coords0 + t1 = [x, y, selu(data@W_lin+b)] ----------------
__global__ __launch_bounds__(256) void prep_k(const float* __restrict__ data,
                                              const float* __restrict__ W,
                                              const float* __restrict__ b,
                                              float* __restrict__ coords0,
                                              unsigned short* __restrict__ t1) {
    int idx = blockIdx.x * blockDim.x + threadIdx.x;
    if (idx >= N_NODES * 256) return;
    int n = idx >> 8, c = idx & 255;
    if (c < 2) {
        float v = data[n * 10 + c];
        t1[(size_t)n * 256 + c] = f2bf(v);
        if (c == 0) {
            coords0[2 * n] = data[n * 10];
            coords0[2 * n + 1] = data[n * 10 + 1];
        }
    } else {
        int cc = c - 2;
        float acc = b[cc];
        const float* dr = data + (size_t)n * 10;
#pragma unroll
        for (int k = 0; k < 10; ++k) acc += dr[k] * W[k * 254 + cc];
        t1[(size_t)n * 256 + c] = f2bf(selu_f(acc));
    }
}

// ---------------- fold all 4 layers in one launch: one wave per (layer,k,h) ----------------
__global__ __launch_bounds__(64) void fold_all_k(
    const float* __restrict__ W0, const float* __restrict__ s0v, const float* __restrict__ d0v,
    const float* __restrict__ W1, const float* __restrict__ s1v, const float* __restrict__ d1v,
    const float* __restrict__ W2, const float* __restrict__ s2v, const float* __restrict__ d2v,
    const float* __restrict__ W3, const float* __restrict__ s3v, const float* __restrict__ d3v,
    float* __restrict__ wsf0, float* __restrict__ wdf0,
    float* __restrict__ wsf1, float* __restrict__ wdf1,
    float* __restrict__ wsf2, float* __restrict__ wdf2,
    float* __restrict__ wsf3, float* __restrict__ wdf3) {
    int bid = blockIdx.x;
    const float* W; const float* sv; const float* dv; float* ws; float* wd;
    int K, C, pair;
    if (bid < 1536)      { W = W0; sv = s0v; dv = d0v; ws = wsf0; wd = wdf0; K = 256; C = 508; pair = bid; }
    else if (bid < 4608) { W = W1; sv = s1v; dv = d1v; ws = wsf1; wd = wdf1; K = 512; C = 250; pair = bid - 1536; }
    else if (bid < 6144) { W = W2; sv = s2v; dv = d2v; ws = wsf2; wd = wdf2; K = 256; C = 120; pair = bid - 4608; }
    else                 { W = W3; sv = s3v; dv = d3v; ws = wsf3; wd = wdf3; K = 128; C = 20;  pair = bid - 6144; }
    int k = pair / HEADS, h = pair % HEADS;
    int lane = threadIdx.x;
    const float* wr = W + (size_t)k * (HEADS * C) + h * C;
    const float* sr = sv + h * C;
    const float* dr = dv + h * C;
    float s = 0.f, d = 0.f;
    for (int c = lane; c < C; c += 64) {
        float w = wr[c];
        s += w * sr[c];
        d += w * dr[c];
    }
#pragma unroll
    for (int off = 32; off > 0; off >>= 1) {
        s += __shfl_xor(s, off);
        d += __shfl_xor(d, off);
    }
    if (lane == 0) { ws[pair] = s; wd[pair] = d; }
}

// ---------------- Vt build for all 3 GEMM layers in one launch ----------------
__global__ __launch_bounds__(256) void convv_all_k(
    const float* __restrict__ W0, unsigned short* __restrict__ Vt0,
    const float* __restrict__ W1, unsigned short* __restrict__ Vt1,
    const float* __restrict__ W2, unsigned short* __restrict__ Vt2) {
    __shared__ float tile[64][65];
    int bid = blockIdx.x;
    const float* W; unsigned short* Vt; int K, C, K6, bid2, ktiles;
    if (bid < 192)      { W = W0; Vt = Vt0; K = 256; C = 508; K6 = 1536; bid2 = bid;       ktiles = 24; }
    else if (bid < 384) { W = W1; Vt = Vt1; K = 512; C = 250; K6 = 3072; bid2 = bid - 192; ktiles = 48; }
    else                { W = W2; Vt = Vt2; K = 256; C = 120; K6 = 1536; bid2 = bid - 384; ktiles = 24; }
    int kb = bid2 % ktiles, cb = bid2 / ktiles;
    const int tx = threadIdx.x;      // 0..63
    const int ty = threadIdx.y;      // 0..3
    const int k0 = kb * 64;
    const int c0 = cb * 64;
    for (int i = ty; i < 64; i += 4) {
        int kk = k0 + i;             // k' = h*K + k
        int h = kk / K, k = kk - h * K;
        int c = c0 + tx;
        tile[i][tx] = (c < C) ? W[(size_t)k * (HEADS * C) + h * C + c] : 0.f;
    }
    __syncthreads();
    for (int i = ty; i < 64; i += 4) {
        int c = c0 + i;
        Vt[(size_t)c * K6 + k0 + tx] = f2bf(tile[tx][i]);
    }
}

// ---------------- split-K MFMA GEMM: partial[kz][m][n] (bf16, no epilogue) ----------------
__global__ __launch_bounds__(256) void gemm_split_k(
    const unsigned short* __restrict__ A,   // bf16 [MPAD][Kpitch]
    const unsigned short* __restrict__ Bt,  // bf16 [Npad][Kpitch]
    unsigned short* __restrict__ part,      // bf16 [KS][MPAD][Npad]
    int Kpitch, int klen, int Npad) {
    __shared__ unsigned short lds[16384];
    const int tid = threadIdx.x;
    const int lane = tid & 63, wid = tid >> 6;
    const int wm = wid >> 1, wn = wid & 1;
    const int m0 = blockIdx.y * 128;
    const int n0 = blockIdx.x * 128;
    const int kz = blockIdx.z;
    const int kbeg = kz * klen;

    f32x4 acc[4][4] = {};

    const unsigned short* gsrc[8];
    unsigned ldsoff[8];
#pragma unroll
    for (int i = 0; i < 8; ++i) {
        const int half = i >> 2;
        const int slot = (i & 3) * 256 + tid;
        const int r = slot >> 3;
        const int c16 = slot & 7;
        const int ksl = c16 ^ (r & 7);
        gsrc[i] = (half ? (Bt + (size_t)(n0 + r) * Kpitch) : (A + (size_t)(m0 + r) * Kpitch)) + ksl * 8;
        ldsoff[i] = (unsigned)(half * 8192 + ((i & 3) * 256 + wid * 64) * 8);
    }

    for (int kt = kbeg; kt < kbeg + klen; kt += 64) {
#pragma unroll
        for (int i = 0; i < 8; ++i) {
            __builtin_amdgcn_global_load_lds(
                (const __attribute__((address_space(1))) unsigned int*)(gsrc[i] + kt),
                (__attribute__((address_space(3))) unsigned int*)(&lds[ldsoff[i]]),
                16, 0, 0);
        }
        __syncthreads();
#pragma unroll
        for (int kc = 0; kc < 2; ++kc) {
            const int xo = (((kc * 4 + (lane >> 4)) ^ (lane & 7)) << 4);
            bf16x8 aop[4], bop[4];
#pragma unroll
            for (int f = 0; f < 4; ++f) {
                const int rA = wm * 64 + f * 16 + (lane & 15);
                bop[f] = *(const bf16x8*)((const char*)lds + rA * 128 + xo);
                const int rB = wn * 64 + f * 16 + (lane & 15);
                aop[f] = *(const bf16x8*)((const char*)lds + 16384 * 1 + rB * 128 + xo);
            }
#pragma unroll
            for (int fm = 0; fm < 4; ++fm)
#pragma unroll
                for (int fn = 0; fn < 4; ++fn)
                    acc[fm][fn] = __builtin_amdgcn_mfma_f32_16x16x32_bf16(
                        aop[fn], bop[fm], acc[fm][fn], 0, 0, 0);
        }
        __syncthreads();
    }

    unsigned short* pbase = part + (size_t)kz * MPAD * Npad;
    const int mrow = m0 + wm * 64 + (lane & 15);
    const int ncol = n0 + wn * 64 + ((lane >> 4) * 4);
#pragma unroll
    for (int fm = 0; fm < 4; ++fm) {
#pragma unroll
        for (int fn = 0; fn < 4; ++fn) {
            f32x4 v = acc[fm][fn];
            unsigned int u0 = (unsigned int)f2bf(v.x) | ((unsigned int)f2bf(v.y) << 16);
            unsigned int u1 = (unsigned int)f2bf(v.z) | ((unsigned int)f2bf(v.w) << 16);
            uint2 pk = make_uint2(u0, u1);
            *(uint2*)&pbase[(size_t)(mrow + fm * 16) * Npad + ncol + fn * 16] = pk;
        }
    }
}

// ---------------- reduce partials + selu epilogue ----------------
__global__ __launch_bounds__(256) void reduce_feat_k(
    const unsigned short* __restrict__ part, unsigned short* __restrict__ tnext,
    int KS, int Npad, int ld, int off, int Cfeat) {
    int idx = blockIdx.x * 256 + threadIdx.x;
    int half = Npad >> 1;
    int r = idx / half, cp = idx - r * half;
    if (r >= N_NODES) return;
    int cb = cp * 2;
    if (cb >= Cfeat) return;
    const unsigned int* pp = (const unsigned int*)part;
    size_t stride = (size_t)MPAD * half;
    size_t base = (size_t)r * half + cp;
    float s0 = 0.f, s1 = 0.f;
    for (int kz = 0; kz < KS; ++kz) {
        unsigned int u = pp[kz * stride + base];
        s0 += bf2f((unsigned short)(u & 0xffff));
        s1 += bf2f((unsigned short)(u >> 16));
    }
    float o0 = selu_f(s0 * (1.f / 6.f));
    float o1 = selu_f(s1 * (1.f / 6.f));
    *(unsigned int*)&tnext[(size_t)r * ld + off + cb] =
        (unsigned int)f2bf(o0) | ((unsigned int)f2bf(o1) << 16);
}

// ---------------- proj: one wave per node ----------------
__global__ __launch_bounds__(256) void proj2_k(const unsigned short* __restrict__ t,
                                               const float* __restrict__ wsf,
                                               const float* __restrict__ wdf,
                                               float* __restrict__ a_s,
                                               float* __restrict__ a_d, int K) {
    const int wv = threadIdx.x >> 6;
    const int lane = threadIdx.x & 63;
    const int n = blockIdx.x * 4 + wv;
    if (n >= N_NODES) return;
    const unsigned short* tr = t + (size_t)n * K;
    const int kpl = K >> 6;
    const int k0 = lane * kpl;

    unsigned int buf[4] = {0u, 0u, 0u, 0u};
    if (kpl == 8) {
        uint4 u = *(const uint4*)(tr + k0);
        buf[0] = u.x; buf[1] = u.y; buf[2] = u.z; buf[3] = u.w;
    } else if (kpl == 4) {
        uint2 u = *(const uint2*)(tr + k0);
        buf[0] = u.x; buf[1] = u.y;
    } else {
        buf[0] = *(const unsigned int*)(tr + k0);
    }

    float s[HEADS] = {}, d[HEADS] = {};
#pragma unroll
    for (int j = 0; j < 8; ++j) {
        if (j >= kpl) break;
        unsigned int w = buf[j >> 1];
        unsigned short u = (j & 1) ? (unsigned short)(w >> 16) : (unsigned short)(w & 0xffff);
        float v = bf2f(u);
        const float* ws = wsf + (size_t)(k0 + j) * HEADS;
        const float* wd = wdf + (size_t)(k0 + j) * HEADS;
#pragma unroll
        for (int h = 0; h < HEADS; ++h) {
            s[h] += v * ws[h];
            d[h] += v * wd[h];
        }
    }
#pragma unroll
    for (int off = 32; off > 0; off >>= 1) {
#pragma unroll
        for (int h = 0; h < HEADS; ++h) {
            s[h] += __shfl_xor(s[h], off);
            d[h] += __shfl_xor(d[h], off);
        }
    }
    if (lane == 0) {
#pragma unroll
        for (int h = 0; h < HEADS; ++h) {
            a_s[n * HEADS + h] = s[h];
            a_d[n * HEADS + h] = d[h];
        }
    }
}

// ---------------- fused softmax + aggregate + move_coords (block per dst node) -------------
__global__ __launch_bounds__(256) void attn_agg_move_k(
    const float* __restrict__ a_s, const float* __restrict__ a_d,
    const int* __restrict__ srcv, const int* __restrict__ csr,
    const int* __restrict__ offs,
    const unsigned short* __restrict__ t_in, unsigned short* __restrict__ thagg,
    int K,                                    // 512 / 256 agg width; 0 = no aggregation
    const float* __restrict__ cprev, const int* __restrict__ bd,
    float* __restrict__ cout, unsigned short* __restrict__ tnext, int ld,
    const float* __restrict__ xA, int offA,
    const float* __restrict__ xB, int offB) {
    const int n = blockIdx.x;
    const int tid = threadIdx.x;
    const int lane = tid & 63, w = tid >> 6;
    const int r0 = offs[n], r1 = offs[n + 1];

    __shared__ float m_sh[HEADS], rd_sh[HEADS], ad_sh[HEADS];
    __shared__ float al_sh[128][HEADS];
    __shared__ int src_sh[128];
    __shared__ float mrg[128][12];
    __shared__ float cxy_sh[2];

    // ---- phase A: online softmax stats per head ----
    for (int h = w; h < HEADS; h += 4) {
        float ad = a_d[n * HEADS + h];
        if (lane == 0) ad_sh[h] = ad;
        float m = -1e30f, s = 0.f;
        for (int i = r0 + lane; i < r1; i += 64) {
            float v = a_s[srcv[csr[i]] * HEADS + h] + ad;
            v = v > 0.f ? v : NEG_SLOPE * v;
            float nm = fmaxf(m, v);
            s = s * __expf(m - nm) + __expf(v - nm);
            m = nm;
        }
#pragma unroll
        for (int off = 32; off > 0; off >>= 1) {
            float mo = __shfl_xor(m, off);
            float so = __shfl_xor(s, off);
            float nm = fmaxf(m, mo);
            s = s * __expf(m - nm) + so * __expf(mo - nm);
            m = nm;
        }
        if (lane == 0) { m_sh[h] = m; rd_sh[h] = (s > 0.f) ? 1.f / s : 0.f; }
    }
    __syncthreads();

    // ---- phase B (chunks of 128 edges) ----
    float acc0[HEADS] = {}, acc1[HEADS] = {};
    float cx = 0.f, cy = 0.f;
    const int th = (K == 256) ? (tid & 127) : tid;
    const int eo = (K == 256) ? (tid >> 7) : 0;
    const int k0 = th * 2;
    for (int base = r0; base < r1; base += 128) {
        int cnt = min(128, r1 - base);
        if (tid < cnt) src_sh[tid] = srcv[csr[base + tid]];
        __syncthreads();
        for (int j = tid; j < cnt * HEADS; j += 256) {
            int i = j / HEADS, h = j - i * HEADS;
            float v = a_s[src_sh[i] * HEADS + h] + ad_sh[h];
            v = v > 0.f ? v : NEG_SLOPE * v;
            al_sh[i][h] = __expf(v - m_sh[h]) * rd_sh[h];
        }
        __syncthreads();
        if (K == 512) {
#pragma unroll 2
            for (int i = 0; i < cnt; ++i) {
                unsigned int u = *(const unsigned int*)(t_in + (size_t)src_sh[i] * 512 + k0);
                float v0 = bf2f((unsigned short)(u & 0xffff));
                float v1 = bf2f((unsigned short)(u >> 16));
#pragma unroll
                for (int h = 0; h < HEADS; ++h) {
                    float a = al_sh[i][h];
                    acc0[h] += a * v0;
                    acc1[h] += a * v1;
                }
            }
        } else if (K == 256) {
            // two 128-thread edge groups, each loads a full dword
#pragma unroll 2
            for (int i = 0; i < cnt; i += 2) {
                int ie = i + eo;
                if (ie < cnt) {
                    unsigned int u = *(const unsigned int*)(t_in + (size_t)src_sh[ie] * 256 + k0);
                    float v0 = bf2f((unsigned short)(u & 0xffff));
                    float v1 = bf2f((unsigned short)(u >> 16));
#pragma unroll
                    for (int h = 0; h < HEADS; ++h) {
                        float a = al_sh[ie][h];
                        acc0[h] += a * v0;
                        acc1[h] += a * v1;
                    }
                }
            }
        }
        if (w == 3) {
            for (int i = lane; i < cnt; i += 64) {
                int s = src_sh[i];
                const float* al = al_sh[i];
                float am = (al[0] + al[1] + al[2] + al[3] + al[4] + al[5]) * (1.f / 6.f);
                cx += am * cprev[2 * s];
                cy += am * cprev[2 * s + 1];
            }
        }
        __syncthreads();
    }

    // ---- phase C ----
    if (K == 512) {
#pragma unroll
        for (int h = 0; h < HEADS; ++h) {
            unsigned int pk = (unsigned int)f2bf(acc0[h]) | ((unsigned int)f2bf(acc1[h]) << 16);
            *(unsigned int*)(thagg + (size_t)n * 3072 + h * 512 + k0) = pk;
        }
    } else if (K == 256) {
        if (eo == 1) {
#pragma unroll
            for (int h = 0; h < HEADS; ++h) { mrg[th][h] = acc0[h]; mrg[th][h + 6] = acc1[h]; }
        }
        __syncthreads();
        if (eo == 0) {
#pragma unroll
            for (int h = 0; h < HEADS; ++h) {
                float s0 = acc0[h] + mrg[th][h];
                float s1 = acc1[h] + mrg[th][h + 6];
                unsigned int pk = (unsigned int)f2bf(s0) | ((unsigned int)f2bf(s1) << 16);
                *(unsigned int*)(thagg + (size_t)n * 1536 + h * 256 + k0) = pk;
            }
        }
    }
    if (w == 3) {
#pragma unroll
        for (int off = 32; off > 0; off >>= 1) {
            cx += __shfl_xor(cx, off);
            cy += __shfl_xor(cy, off);
        }
        if (lane == 0) { cxy_sh[0] = cx; cxy_sh[1] = cy; }
    }
    __syncthreads();
    if (tid == 0) {
        float px = cprev[2 * n], py = cprev[2 * n + 1];
        float ocx, ocy;
        if (bd[n] != 0) { ocx = px; ocy = py; }
        else { ocx = cxy_sh[0]; ocy = cxy_sh[1]; }
        cout[2 * n] = ocx; cout[2 * n + 1] = ocy;
        if (tnext) {
            unsigned short* row = tnext + (size_t)n * ld;
            row[0] = f2bf(ocx); row[1] = f2bf(ocy);
            row[2] = f2bf(px);  row[3] = f2bf(py);
            if (xA) { row[offA] = f2bf(xA[2 * n]); row[offA + 1] = f2bf(xA[2 * n + 1]); }
            if (xB) { row[offB] = f2bf(xB[2 * n]); row[offB + 1] = f2bf(xB[2 * n + 1]); }
        }
    }
}

static inline int cdiv(int a, int b) { return (a + b - 1) / b; }

extern "C" void kernel_launch(void* const* d_in, const int* in_sizes, int n_in,
                              void* d_out, int out_size, void* d_ws, size_t ws_size,
                              hipStream_t stream) {
    const float* data = (const float*)d_in[0];
    const int* eidx = (const int*)d_in[1];
    const int* bd = (const int*)d_in[2];
    const float* W_lin = (const float*)d_in[4];
    const float* b_lin = (const float*)d_in[5];
    const float* Wl[4]  = {(const float*)d_in[6],  (const float*)d_in[9],
                           (const float*)d_in[12], (const float*)d_in[15]};
    const float* Asrc[4] = {(const float*)d_in[7],  (const float*)d_in[10],
                            (const float*)d_in[13], (const float*)d_in[16]};
    const float* Adst[4] = {(const float*)d_in[8],  (const float*)d_in[11],
                            (const float*)d_in[14], (const float*)d_in[17]};
    const int Kd[4] = {256, 512, 256, 128};
    const int Cd[4] = {508, 250, 120, 20};
    const int Cpadd[4] = {512, 256, 128, 0};
    const int KSd[4] = {2, 4, 4, 0};

    const int* srcv = eidx;
    const int* dstv = eidx + N_EDGES;

    char* p = (char*)d_ws;
    auto alloc = [&](size_t bytes) -> void* {
        void* r = (void*)p;
        p += (bytes + 255) & ~(size_t)255;
        return r;
    };
    unsigned short* tb1 = (unsigned short*)alloc((size_t)MPAD * 256 * 2);
    unsigned short* tb2 = (unsigned short*)alloc((size_t)MPAD * 512 * 2);
    unsigned short* tb3 = (unsigned short*)alloc((size_t)MPAD * 256 * 2);
    unsigned short* tb4 = (unsigned short*)alloc((size_t)MPAD * 128 * 2);
    unsigned short* thagg = (unsigned short*)alloc((size_t)MPAD * 3072 * 2);
    unsigned short* VtL[3];
    VtL[0] = (unsigned short*)alloc((size_t)512 * 1536 * 2);
    VtL[1] = (unsigned short*)alloc((size_t)256 * 3072 * 2);
    VtL[2] = (unsigned short*)alloc((size_t)128 * 1536 * 2);
    unsigned short* partb = (unsigned short*)alloc((size_t)8 * MPAD * 256 * 2);
    float* coords0 = (float*)alloc((size_t)N_NODES * 2 * 4);
    float* c1 = (float*)alloc((size_t)N_NODES * 2 * 4);
    float* c2 = (float*)alloc((size_t)N_NODES * 2 * 4);
    float* c3 = (float*)alloc((size_t)N_NODES * 2 * 4);
    float* a_s = (float*)alloc((size_t)N_NODES * HEADS * 4);
    float* a_d = (float*)alloc((size_t)N_NODES * HEADS * 4);
    float* wsfL[4]; float* wdfL[4];
    wsfL[0] = (float*)alloc(1536 * 4); wdfL[0] = (float*)alloc(1536 * 4);
    wsfL[1] = (float*)alloc(3072 * 4); wdfL[1] = (float*)alloc(3072 * 4);
    wsfL[2] = (float*)alloc(1536 * 4); wdfL[2] = (float*)alloc(1536 * 4);
    wsfL[3] = (float*)alloc(768 * 4);  wdfL[3] = (float*)alloc(768 * 4);
    int* counts = (int*)alloc((size_t)N_NODES * 4);   // counts+cursor adjacent: one memset
    int* cursor = (int*)alloc((size_t)N_NODES * 4);
    int* offs = (int*)alloc((size_t)(N_NODES + 1) * 4);
    int* csr = (int*)alloc((size_t)N_EDGES * 4);

    // one memset covers counts + cursor (adjacent carve, 256B-aligned blocks)
    hipMemsetAsync(counts, 0, (size_t)((char*)offs - (char*)counts), stream);
    count_edges_k<<<cdiv(N_EDGES, 256), 256, 0, stream>>>(dstv, counts);
    scan_k<<<1, 1024, 0, stream>>>(counts, offs);
    fill_csr_k<<<cdiv(N_EDGES, 256), 256, 0, stream>>>(dstv, offs, cursor, csr);

    prep_k<<<cdiv(N_NODES * 256, 256), 256, 0, stream>>>(data, W_lin, b_lin, coords0, tb1);
    fold_all_k<<<6912, 64, 0, stream>>>(
        Wl[0], Asrc[0], Adst[0], Wl[1], Asrc[1], Adst[1],
        Wl[2], Asrc[2], Adst[2], Wl[3], Asrc[3], Adst[3],
        wsfL[0], wdfL[0], wsfL[1], wdfL[1], wsfL[2], wdfL[2], wsfL[3], wdfL[3]);
    convv_all_k<<<432, dim3(64, 4), 0, stream>>>(Wl[0], VtL[0], Wl[1], VtL[1], Wl[2], VtL[2]);

    unsigned short* tin[4]   = {tb1, tb2, tb3, tb4};
    unsigned short* tnext[4] = {tb2, tb3, tb4, nullptr};
    int ldn[4]  = {512, 256, 128, 0};
    int foff[4] = {4, 6, 8, 0};
    float* cprev[4] = {coords0, c1, c2, c3};
    float* cout[4]  = {c1, c2, c3, (float*)d_out};
    const float* xAv[4] = {nullptr, coords0, c1, nullptr};
    int offAv[4] = {0, 4, 4, 0};
    const float* xBv[4] = {nullptr, nullptr, coords0, nullptr};
    int offBv[4] = {0, 0, 6, 0};

    for (int l = 0; l < 4; ++l) {
        int K = Kd[l], C = Cd[l], Cpad = Cpadd[l], KS = KSd[l];
        int K6 = K * HEADS;
        proj2_k<<<cdiv(N_NODES, 4), 256, 0, stream>>>(tin[l], wsfL[l], wdfL[l], a_s, a_d, K);

        attn_agg_move_k<<<N_NODES, 256, 0, stream>>>(
            a_s, a_d, srcv, csr, offs,
            tin[l], (l < 3) ? thagg : nullptr, (l < 3) ? K : 0,
            cprev[l], bd, cout[l], tnext[l], ldn[l],
            xAv[l], offAv[l], xBv[l], offBv[l]);

        if (l < 3) {
            int klen = K6 / KS;
            gemm_split_k<<<dim3(Cpad / 128, MPAD / 128, KS), 256, 0, stream>>>(
                thagg, VtL[l], partb, K6, klen, Cpad);
            reduce_feat_k<<<cdiv(MPAD * (Cpad / 2), 256), 256, 0, stream>>>(
                partb, tnext[l], KS, Cpad, ldn[l], foff[l], C);
        }
    }
}

// Round 10
// 347.934 us; speedup vs baseline: 1.5523x; 1.0701x over previous
//
#include <hip/hip_runtime.h>
#include <hip/hip_bf16.h>

#define N_NODES 10000
#define N_EDGES 70000
#define HEADS 6
#define MPAD 10112            // ceil(10000/128)*128
#define SELU_SCALE 1.0507009873554805f
#define SELU_ALPHA  1.6732632423543772f
#define NEG_SLOPE 0.2f

typedef __attribute__((ext_vector_type(8))) __bf16 bf16x8;
typedef __attribute__((ext_vector_type(4))) float f32x4;

__device__ __forceinline__ float selu_f(float x) {
    return x > 0.f ? SELU_SCALE * x : SELU_SCALE * SELU_ALPHA * (__expf(x) - 1.f);
}
__device__ __forceinline__ unsigned short f2bf(float f) {
    __hip_bfloat16 h = __float2bfloat16(f);
    return __builtin_bit_cast(unsigned short, h);
}
__device__ __forceinline__ float bf2f(unsigned short u) {
    unsigned int x = ((unsigned int)u) << 16;
    return __builtin_bit_cast(float, x);
}

// ---------------- CSR build ----------------
__global__ void count_edges_k(const int* __restrict__ dstv, int* __restrict__ counts) {
    int e = blockIdx.x * blockDim.x + threadIdx.x;
    if (e < N_EDGES) atomicAdd(&counts[dstv[e]], 1);
}

__global__ __launch_bounds__(1024) void scan_k(const int* __restrict__ counts, int* __restrict__ offs) {
    __shared__ int part[1024];
    int tid = threadIdx.x;
    const int per = (N_NODES + 1023) / 1024;  // 10
    int start = tid * per;
    int s = 0;
    for (int i = 0; i < per; ++i) { int idx = start + i; if (idx < N_NODES) s += counts[idx]; }
    part[tid] = s;
    __syncthreads();
    for (int off = 1; off < 1024; off <<= 1) {
        int v = (tid >= off) ? part[tid - off] : 0;
        __syncthreads();
        part[tid] += v;
        __syncthreads();
    }
    int run = part[tid] - s;
    for (int i = 0; i < per; ++i) {
        int idx = start + i;
        if (idx < N_NODES) { offs[idx] = run; run += counts[idx]; }
    }
    if (tid == 0) offs[N_NODES] = part[1023];
}

__global__ void fill_csr_k(const int* __restrict__ dstv, const int* __restrict__ offs,
                           int* __restrict__ cursor, int* __restrict__ csr) {
    int e = blockIdx.x * blockDim.x + threadIdx.x;
    if (e < N_EDGES) {
        int d = dstv[e];
        int pos = atomicAdd(&cursor[d], 1);
        csr[offs[d] + pos] = e;
    }
}

// ---------------- prep: coords0 + t1 = [x, y, selu(data@W_lin+b)] ----------------
__global__ __launch_bounds__(256) void prep_k(const float* __restrict__ data,
                                              const float* __restrict__ W,
                                              const float* __restrict__ b,
                                              float* __restrict__ coords0,
                                              unsigned short* __restrict__ t1) {
    int idx = blockIdx.x * blockDim.x + threadIdx.x;
    if (idx >= N_NODES * 256) return;
    int n = idx >> 8, c = idx & 255;
    if (c < 2) {
        float v = data[n * 10 + c];
        t1[(size_t)n * 256 + c] = f2bf(v);
        if (c == 0) {
            coords0[2 * n] = data[n * 10];
            coords0[2 * n + 1] = data[n * 10 + 1];
        }
    } else {
        int cc = c - 2;
        float acc = b[cc];
        const float* dr = data + (size_t)n * 10;
#pragma unroll
        for (int k = 0; k < 10; ++k) acc += dr[k] * W[k * 254 + cc];
        t1[(size_t)n * 256 + c] = f2bf(selu_f(acc));
    }
}

// ---------------- fold all 4 layers in one launch: one wave per (layer,k,h) ----------------
__global__ __launch_bounds__(64) void fold_all_k(
    const float* __restrict__ W0, const float* __restrict__ s0v, const float* __restrict__ d0v,
    const float* __restrict__ W1, const float* __restrict__ s1v, const float* __restrict__ d1v,
    const float* __restrict__ W2, const float* __restrict__ s2v, const float* __restrict__ d2v,
    const float* __restrict__ W3, const float* __restrict__ s3v, const float* __restrict__ d3v,
    float* __restrict__ wsf0, float* __restrict__ wdf0,
    float* __restrict__ wsf1, float* __restrict__ wdf1,
    float* __restrict__ wsf2, float* __restrict__ wdf2,
    float* __restrict__ wsf3, float* __restrict__ wdf3) {
    int bid = blockIdx.x;
    const float* W; const float* sv; const float* dv; float* ws; float* wd;
    int K, C, pair;
    if (bid < 1536)      { W = W0; sv = s0v; dv = d0v; ws = wsf0; wd = wdf0; K = 256; C = 508; pair = bid; }
    else if (bid < 4608) { W = W1; sv = s1v; dv = d1v; ws = wsf1; wd = wdf1; K = 512; C = 250; pair = bid - 1536; }
    else if (bid < 6144) { W = W2; sv = s2v; dv = d2v; ws = wsf2; wd = wdf2; K = 256; C = 120; pair = bid - 4608; }
    else                 { W = W3; sv = s3v; dv = d3v; ws = wsf3; wd = wdf3; K = 128; C = 20;  pair = bid - 6144; }
    int k = pair / HEADS, h = pair % HEADS;
    int lane = threadIdx.x;
    const float* wr = W + (size_t)k * (HEADS * C) + h * C;
    const float* sr = sv + h * C;
    const float* dr = dv + h * C;
    float s = 0.f, d = 0.f;
    for (int c = lane; c < C; c += 64) {
        float w = wr[c];
        s += w * sr[c];
        d += w * dr[c];
    }
#pragma unroll
    for (int off = 32; off > 0; off >>= 1) {
        s += __shfl_xor(s, off);
        d += __shfl_xor(d, off);
    }
    if (lane == 0) { ws[pair] = s; wd[pair] = d; }
}

// ---------------- Vt build for all 3 GEMM layers in one launch ----------------
__global__ __launch_bounds__(256) void convv_all_k(
    const float* __restrict__ W0, unsigned short* __restrict__ Vt0,
    const float* __restrict__ W1, unsigned short* __restrict__ Vt1,
    const float* __restrict__ W2, unsigned short* __restrict__ Vt2) {
    __shared__ float tile[64][65];
    int bid = blockIdx.x;
    const float* W; unsigned short* Vt; int K, C, K6, bid2, ktiles;
    if (bid < 192)      { W = W0; Vt = Vt0; K = 256; C = 508; K6 = 1536; bid2 = bid;       ktiles = 24; }
    else if (bid < 384) { W = W1; Vt = Vt1; K = 512; C = 250; K6 = 3072; bid2 = bid - 192; ktiles = 48; }
    else                { W = W2; Vt = Vt2; K = 256; C = 120; K6 = 1536; bid2 = bid - 384; ktiles = 24; }
    int kb = bid2 % ktiles, cb = bid2 / ktiles;
    const int tx = threadIdx.x;
    const int ty = threadIdx.y;
    const int k0 = kb * 64;
    const int c0 = cb * 64;
    for (int i = ty; i < 64; i += 4) {
        int kk = k0 + i;
        int h = kk / K, k = kk - h * K;
        int c = c0 + tx;
        tile[i][tx] = (c < C) ? W[(size_t)k * (HEADS * C) + h * C + c] : 0.f;
    }
    __syncthreads();
    for (int i = ty; i < 64; i += 4) {
        int c = c0 + i;
        Vt[(size_t)c * K6 + k0 + tx] = f2bf(tile[tx][i]);
    }
}

// ---------------- split-K MFMA GEMM: partial[kz][m][n] (bf16, no epilogue) ----------------
__global__ __launch_bounds__(256) void gemm_split_k(
    const unsigned short* __restrict__ A,
    const unsigned short* __restrict__ Bt,
    unsigned short* __restrict__ part,
    int Kpitch, int klen, int Npad) {
    __shared__ unsigned short lds[16384];
    const int tid = threadIdx.x;
    const int lane = tid & 63, wid = tid >> 6;
    const int wm = wid >> 1, wn = wid & 1;
    const int m0 = blockIdx.y * 128;
    const int n0 = blockIdx.x * 128;
    const int kz = blockIdx.z;
    const int kbeg = kz * klen;

    f32x4 acc[4][4] = {};

    const unsigned short* gsrc[8];
    unsigned ldsoff[8];
#pragma unroll
    for (int i = 0; i < 8; ++i) {
        const int half = i >> 2;
        const int slot = (i & 3) * 256 + tid;
        const int r = slot >> 3;
        const int c16 = slot & 7;
        const int ksl = c16 ^ (r & 7);
        gsrc[i] = (half ? (Bt + (size_t)(n0 + r) * Kpitch) : (A + (size_t)(m0 + r) * Kpitch)) + ksl * 8;
        ldsoff[i] = (unsigned)(half * 8192 + ((i & 3) * 256 + wid * 64) * 8);
    }

    for (int kt = kbeg; kt < kbeg + klen; kt += 64) {
#pragma unroll
        for (int i = 0; i < 8; ++i) {
            __builtin_amdgcn_global_load_lds(
                (const __attribute__((address_space(1))) unsigned int*)(gsrc[i] + kt),
                (__attribute__((address_space(3))) unsigned int*)(&lds[ldsoff[i]]),
                16, 0, 0);
        }
        __syncthreads();
#pragma unroll
        for (int kc = 0; kc < 2; ++kc) {
            const int xo = (((kc * 4 + (lane >> 4)) ^ (lane & 7)) << 4);
            bf16x8 aop[4], bop[4];
#pragma unroll
            for (int f = 0; f < 4; ++f) {
                const int rA = wm * 64 + f * 16 + (lane & 15);
                bop[f] = *(const bf16x8*)((const char*)lds + rA * 128 + xo);
                const int rB = wn * 64 + f * 16 + (lane & 15);
                aop[f] = *(const bf16x8*)((const char*)lds + 16384 * 1 + rB * 128 + xo);
            }
#pragma unroll
            for (int fm = 0; fm < 4; ++fm)
#pragma unroll
                for (int fn = 0; fn < 4; ++fn)
                    acc[fm][fn] = __builtin_amdgcn_mfma_f32_16x16x32_bf16(
                        aop[fn], bop[fm], acc[fm][fn], 0, 0, 0);
        }
        __syncthreads();
    }

    unsigned short* pbase = part + (size_t)kz * MPAD * Npad;
    const int mrow = m0 + wm * 64 + (lane & 15);
    const int ncol = n0 + wn * 64 + ((lane >> 4) * 4);
#pragma unroll
    for (int fm = 0; fm < 4; ++fm) {
#pragma unroll
        for (int fn = 0; fn < 4; ++fn) {
            f32x4 v = acc[fm][fn];
            unsigned int u0 = (unsigned int)f2bf(v.x) | ((unsigned int)f2bf(v.y) << 16);
            unsigned int u1 = (unsigned int)f2bf(v.z) | ((unsigned int)f2bf(v.w) << 16);
            uint2 pk = make_uint2(u0, u1);
            *(uint2*)&pbase[(size_t)(mrow + fm * 16) * Npad + ncol + fn * 16] = pk;
        }
    }
}

// ---------------- reduce partials + selu epilogue ----------------
__global__ __launch_bounds__(256) void reduce_feat_k(
    const unsigned short* __restrict__ part, unsigned short* __restrict__ tnext,
    int KS, int Npad, int ld, int off, int Cfeat) {
    int idx = blockIdx.x * 256 + threadIdx.x;
    int half = Npad >> 1;
    int r = idx / half, cp = idx - r * half;
    if (r >= N_NODES) return;
    int cb = cp * 2;
    if (cb >= Cfeat) return;
    const unsigned int* pp = (const unsigned int*)part;
    size_t stride = (size_t)MPAD * half;
    size_t base = (size_t)r * half + cp;
    float s0 = 0.f, s1 = 0.f;
    for (int kz = 0; kz < KS; ++kz) {
        unsigned int u = pp[kz * stride + base];
        s0 += bf2f((unsigned short)(u & 0xffff));
        s1 += bf2f((unsigned short)(u >> 16));
    }
    float o0 = selu_f(s0 * (1.f / 6.f));
    float o1 = selu_f(s1 * (1.f / 6.f));
    *(unsigned int*)&tnext[(size_t)r * ld + off + cb] =
        (unsigned int)f2bf(o0) | ((unsigned int)f2bf(o1) << 16);
}

// ---------------- proj: one wave per node ----------------
__global__ __launch_bounds__(256) void proj2_k(const unsigned short* __restrict__ t,
                                               const float* __restrict__ wsf,
                                               const float* __restrict__ wdf,
                                               float* __restrict__ a_s,
                                               float* __restrict__ a_d, int K) {
    const int wv = threadIdx.x >> 6;
    const int lane = threadIdx.x & 63;
    const int n = blockIdx.x * 4 + wv;
    if (n >= N_NODES) return;
    const unsigned short* tr = t + (size_t)n * K;
    const int kpl = K >> 6;
    const int k0 = lane * kpl;

    unsigned int buf[4] = {0u, 0u, 0u, 0u};
    if (kpl == 8) {
        uint4 u = *(const uint4*)(tr + k0);
        buf[0] = u.x; buf[1] = u.y; buf[2] = u.z; buf[3] = u.w;
    } else if (kpl == 4) {
        uint2 u = *(const uint2*)(tr + k0);
        buf[0] = u.x; buf[1] = u.y;
    } else {
        buf[0] = *(const unsigned int*)(tr + k0);
    }

    float s[HEADS] = {}, d[HEADS] = {};
#pragma unroll
    for (int j = 0; j < 8; ++j) {
        if (j >= kpl) break;
        unsigned int w = buf[j >> 1];
        unsigned short u = (j & 1) ? (unsigned short)(w >> 16) : (unsigned short)(w & 0xffff);
        float v = bf2f(u);
        const float* ws = wsf + (size_t)(k0 + j) * HEADS;
        const float* wd = wdf + (size_t)(k0 + j) * HEADS;
#pragma unroll
        for (int h = 0; h < HEADS; ++h) {
            s[h] += v * ws[h];
            d[h] += v * wd[h];
        }
    }
#pragma unroll
    for (int off = 32; off > 0; off >>= 1) {
#pragma unroll
        for (int h = 0; h < HEADS; ++h) {
            s[h] += __shfl_xor(s[h], off);
            d[h] += __shfl_xor(d[h], off);
        }
    }
    if (lane == 0) {
#pragma unroll
        for (int h = 0; h < HEADS; ++h) {
            a_s[n * HEADS + h] = s[h];
            a_d[n * HEADS + h] = d[h];
        }
    }
}

// ---------------- fused softmax + aggregate + move_coords: ONE WAVE PER NODE ---------------
// Zero LDS, zero __syncthreads. Lane l owns k-slice [l*KPL, l*KPL+KPL) of all 6 head
// accumulators. Edge src broadcast via __shfl; alpha recomputed per lane from broadcast
// a_s loads (single transaction). KT = 512 / 256 (agg width) / 0 (coords only).
template<int KT>
__global__ __launch_bounds__(256) void attn_agg_move_k(
    const float* __restrict__ a_s, const float* __restrict__ a_d,
    const int* __restrict__ srcv, const int* __restrict__ csr,
    const int* __restrict__ offs,
    const unsigned short* __restrict__ t_in, unsigned short* __restrict__ thagg,
    const float* __restrict__ cprev, const int* __restrict__ bd,
    float* __restrict__ cout, unsigned short* __restrict__ tnext, int ld,
    const float* __restrict__ xA, int offA,
    const float* __restrict__ xB, int offB) {
    const int wid = threadIdx.x >> 6, lane = threadIdx.x & 63;
    const int n = blockIdx.x * 4 + wid;
    if (n >= N_NODES) return;
    const int r0 = offs[n], r1 = offs[n + 1];

    float ad[HEADS], mm[HEADS], ss[HEADS];
#pragma unroll
    for (int h = 0; h < HEADS; ++h) {
        ad[h] = a_d[n * HEADS + h];          // same addr across lanes: broadcast
        mm[h] = -1e30f; ss[h] = 0.f;
    }

    // ---- phase A: per-head online softmax stats, edges striped by lane ----
    for (int base = r0; base < r1; base += 64) {
        int i = base + lane;
        if (i < r1) {
            int src = srcv[csr[i]];
#pragma unroll
            for (int h = 0; h < HEADS; ++h) {
                float v = a_s[src * HEADS + h] + ad[h];
                v = v > 0.f ? v : NEG_SLOPE * v;
                float nm = fmaxf(mm[h], v);
                ss[h] = ss[h] * __expf(mm[h] - nm) + __expf(v - nm);
                mm[h] = nm;
            }
        }
    }
#pragma unroll
    for (int off = 32; off > 0; off >>= 1) {
#pragma unroll
        for (int h = 0; h < HEADS; ++h) {
            float mo = __shfl_xor(mm[h], off);
            float so = __shfl_xor(ss[h], off);
            float nm = fmaxf(mm[h], mo);
            ss[h] = ss[h] * __expf(mm[h] - nm) + so * __expf(mo - nm);
            mm[h] = nm;
        }
    }
    float rd[HEADS];
#pragma unroll
    for (int h = 0; h < HEADS; ++h) rd[h] = ss[h] > 0.f ? 1.f / ss[h] : 0.f;

    // ---- phase B: aggregation + coord centroid ----
    constexpr int KPL = (KT > 0) ? (KT / 64) : 1;
    float acc[HEADS][KPL] = {};
    float cx = 0.f, cy = 0.f;
    for (int base = r0; base < r1; base += 64) {
        int i = base + lane;
        bool ok = i < r1;
        int mysrc = ok ? srcv[csr[i]] : 0;
        if (ok) {   // my-edge mean-alpha for coord centroid (per-lane gather)
            float am = 0.f;
#pragma unroll
            for (int h = 0; h < HEADS; ++h) {
                float v = a_s[mysrc * HEADS + h] + ad[h];
                v = v > 0.f ? v : NEG_SLOPE * v;
                am += __expf(v - mm[h]) * rd[h];
            }
            am *= (1.f / 6.f);
            cx += am * cprev[2 * mysrc];
            cy += am * cprev[2 * mysrc + 1];
        }
        if constexpr (KT > 0) {
            int cnt = min(64, r1 - base);
            for (int j = 0; j < cnt; ++j) {
                int src = __shfl(mysrc, j);
                float al[HEADS];
#pragma unroll
                for (int h = 0; h < HEADS; ++h) {
                    float v = a_s[src * HEADS + h] + ad[h];   // broadcast load
                    v = v > 0.f ? v : NEG_SLOPE * v;
                    al[h] = __expf(v - mm[h]) * rd[h];
                }
                if constexpr (KT == 512) {
                    uint4 u = *(const uint4*)(t_in + (size_t)src * 512 + lane * 8);
                    float tv[8];
                    tv[0] = bf2f((unsigned short)(u.x & 0xffff)); tv[1] = bf2f((unsigned short)(u.x >> 16));
                    tv[2] = bf2f((unsigned short)(u.y & 0xffff)); tv[3] = bf2f((unsigned short)(u.y >> 16));
                    tv[4] = bf2f((unsigned short)(u.z & 0xffff)); tv[5] = bf2f((unsigned short)(u.z >> 16));
                    tv[6] = bf2f((unsigned short)(u.w & 0xffff)); tv[7] = bf2f((unsigned short)(u.w >> 16));
#pragma unroll
                    for (int h = 0; h < HEADS; ++h)
#pragma unroll
                        for (int q = 0; q < 8; ++q) acc[h][q] += al[h] * tv[q];
                } else {
                    uint2 u = *(const uint2*)(t_in + (size_t)src * 256 + lane * 4);
                    float tv[4];
                    tv[0] = bf2f((unsigned short)(u.x & 0xffff)); tv[1] = bf2f((unsigned short)(u.x >> 16));
                    tv[2] = bf2f((unsigned short)(u.y & 0xffff)); tv[3] = bf2f((unsigned short)(u.y >> 16));
#pragma unroll
                    for (int h = 0; h < HEADS; ++h)
#pragma unroll
                        for (int q = 0; q < 4; ++q) acc[h][q] += al[h] * tv[q];
                }
            }
        }
    }

    // ---- phase C: writes ----
    if constexpr (KT == 512) {
#pragma unroll
        for (int h = 0; h < HEADS; ++h) {
            uint4 pk;
            pk.x = (unsigned int)f2bf(acc[h][0]) | ((unsigned int)f2bf(acc[h][1]) << 16);
            pk.y = (unsigned int)f2bf(acc[h][2]) | ((unsigned int)f2bf(acc[h][3]) << 16);
            pk.z = (unsigned int)f2bf(acc[h][4]) | ((unsigned int)f2bf(acc[h][5]) << 16);
            pk.w = (unsigned int)f2bf(acc[h][6]) | ((unsigned int)f2bf(acc[h][7]) << 16);
            *(uint4*)(thagg + (size_t)n * 3072 + h * 512 + lane * 8) = pk;
        }
    } else if constexpr (KT == 256) {
#pragma unroll
        for (int h = 0; h < HEADS; ++h) {
            uint2 pk;
            pk.x = (unsigned int)f2bf(acc[h][0]) | ((unsigned int)f2bf(acc[h][1]) << 16);
            pk.y = (unsigned int)f2bf(acc[h][2]) | ((unsigned int)f2bf(acc[h][3]) << 16);
            *(uint2*)(thagg + (size_t)n * 1536 + h * 256 + lane * 4) = pk;
        }
    }
#pragma unroll
    for (int off = 32; off > 0; off >>= 1) {
        cx += __shfl_xor(cx, off);
        cy += __shfl_xor(cy, off);
    }
    if (lane == 0) {
        float px = cprev[2 * n], py = cprev[2 * n + 1];
        float ocx, ocy;
        if (bd[n] != 0) { ocx = px; ocy = py; }
        else { ocx = cx; ocy = cy; }
        cout[2 * n] = ocx; cout[2 * n + 1] = ocy;
        if (tnext) {
            unsigned short* row = tnext + (size_t)n * ld;
            row[0] = f2bf(ocx); row[1] = f2bf(ocy);
            row[2] = f2bf(px);  row[3] = f2bf(py);
            if (xA) { row[offA] = f2bf(xA[2 * n]); row[offA + 1] = f2bf(xA[2 * n + 1]); }
            if (xB) { row[offB] = f2bf(xB[2 * n]); row[offB + 1] = f2bf(xB[2 * n + 1]); }
        }
    }
}

static inline int cdiv(int a, int b) { return (a + b - 1) / b; }

extern "C" void kernel_launch(void* const* d_in, const int* in_sizes, int n_in,
                              void* d_out, int out_size, void* d_ws, size_t ws_size,
                              hipStream_t stream) {
    const float* data = (const float*)d_in[0];
    const int* eidx = (const int*)d_in[1];
    const int* bd = (const int*)d_in[2];
    const float* W_lin = (const float*)d_in[4];
    const float* b_lin = (const float*)d_in[5];
    const float* Wl[4]  = {(const float*)d_in[6],  (const float*)d_in[9],
                           (const float*)d_in[12], (const float*)d_in[15]};
    const float* Asrc[4] = {(const float*)d_in[7],  (const float*)d_in[10],
                            (const float*)d_in[13], (const float*)d_in[16]};
    const float* Adst[4] = {(const float*)d_in[8],  (const float*)d_in[11],
                            (const float*)d_in[14], (const float*)d_in[17]};
    const int Kd[4] = {256, 512, 256, 128};
    const int Cd[4] = {508, 250, 120, 20};
    const int Cpadd[4] = {512, 256, 128, 0};
    const int KSd[4] = {2, 4, 4, 0};

    const int* srcv = eidx;
    const int* dstv = eidx + N_EDGES;

    char* p = (char*)d_ws;
    auto alloc = [&](size_t bytes) -> void* {
        void* r = (void*)p;
        p += (bytes + 255) & ~(size_t)255;
        return r;
    };
    unsigned short* tb1 = (unsigned short*)alloc((size_t)MPAD * 256 * 2);
    unsigned short* tb2 = (unsigned short*)alloc((size_t)MPAD * 512 * 2);
    unsigned short* tb3 = (unsigned short*)alloc((size_t)MPAD * 256 * 2);
    unsigned short* tb4 = (unsigned short*)alloc((size_t)MPAD * 128 * 2);
    unsigned short* thagg = (unsigned short*)alloc((size_t)MPAD * 3072 * 2);
    unsigned short* VtL[3];
    VtL[0] = (unsigned short*)alloc((size_t)512 * 1536 * 2);
    VtL[1] = (unsigned short*)alloc((size_t)256 * 3072 * 2);
    VtL[2] = (unsigned short*)alloc((size_t)128 * 1536 * 2);
    unsigned short* partb = (unsigned short*)alloc((size_t)8 * MPAD * 256 * 2);
    float* coords0 = (float*)alloc((size_t)N_NODES * 2 * 4);
    float* c1 = (float*)alloc((size_t)N_NODES * 2 * 4);
    float* c2 = (float*)alloc((size_t)N_NODES * 2 * 4);
    float* c3 = (float*)alloc((size_t)N_NODES * 2 * 4);
    float* a_s = (float*)alloc((size_t)N_NODES * HEADS * 4);
    float* a_d = (float*)alloc((size_t)N_NODES * HEADS * 4);
    float* wsfL[4]; float* wdfL[4];
    wsfL[0] = (float*)alloc(1536 * 4); wdfL[0] = (float*)alloc(1536 * 4);
    wsfL[1] = (float*)alloc(3072 * 4); wdfL[1] = (float*)alloc(3072 * 4);
    wsfL[2] = (float*)alloc(1536 * 4); wdfL[2] = (float*)alloc(1536 * 4);
    wsfL[3] = (float*)alloc(768 * 4);  wdfL[3] = (float*)alloc(768 * 4);
    int* counts = (int*)alloc((size_t)N_NODES * 4);   // counts+cursor adjacent: one memset
    int* cursor = (int*)alloc((size_t)N_NODES * 4);
    int* offs = (int*)alloc((size_t)(N_NODES + 1) * 4);
    int* csr = (int*)alloc((size_t)N_EDGES * 4);

    hipMemsetAsync(counts, 0, (size_t)((char*)offs - (char*)counts), stream);
    count_edges_k<<<cdiv(N_EDGES, 256), 256, 0, stream>>>(dstv, counts);
    scan_k<<<1, 1024, 0, stream>>>(counts, offs);
    fill_csr_k<<<cdiv(N_EDGES, 256), 256, 0, stream>>>(dstv, offs, cursor, csr);

    prep_k<<<cdiv(N_NODES * 256, 256), 256, 0, stream>>>(data, W_lin, b_lin, coords0, tb1);
    fold_all_k<<<6912, 64, 0, stream>>>(
        Wl[0], Asrc[0], Adst[0], Wl[1], Asrc[1], Adst[1],
        Wl[2], Asrc[2], Adst[2], Wl[3], Asrc[3], Adst[3],
        wsfL[0], wdfL[0], wsfL[1], wdfL[1], wsfL[2], wdfL[2], wsfL[3], wdfL[3]);
    convv_all_k<<<432, dim3(64, 4), 0, stream>>>(Wl[0], VtL[0], Wl[1], VtL[1], Wl[2], VtL[2]);

    unsigned short* tin[4]   = {tb1, tb2, tb3, tb4};
    unsigned short* tnext[4] = {tb2, tb3, tb4, nullptr};
    int ldn[4]  = {512, 256, 128, 0};
    int foff[4] = {4, 6, 8, 0};
    float* cprev[4] = {coords0, c1, c2, c3};
    float* cout[4]  = {c1, c2, c3, (float*)d_out};
    const float* xAv[4] = {nullptr, coords0, c1, nullptr};
    int offAv[4] = {0, 4, 4, 0};
    const float* xBv[4] = {nullptr, nullptr, coords0, nullptr};
    int offBv[4] = {0, 0, 6, 0};

    for (int l = 0; l < 4; ++l) {
        int K = Kd[l], C = Cd[l], Cpad = Cpadd[l], KS = KSd[l];
        int K6 = K * HEADS;
        proj2_k<<<cdiv(N_NODES, 4), 256, 0, stream>>>(tin[l], wsfL[l], wdfL[l], a_s, a_d, K);

        if (l == 3) {
            attn_agg_move_k<0><<<cdiv(N_NODES, 4), 256, 0, stream>>>(
                a_s, a_d, srcv, csr, offs, tin[l], nullptr,
                cprev[l], bd, cout[l], tnext[l], ldn[l],
                xAv[l], offAv[l], xBv[l], offBv[l]);
        } else if (K == 512) {
            attn_agg_move_k<512><<<cdiv(N_NODES, 4), 256, 0, stream>>>(
                a_s, a_d, srcv, csr, offs, tin[l], thagg,
                cprev[l], bd, cout[l], tnext[l], ldn[l],
                xAv[l], offAv[l], xBv[l], offBv[l]);
        } else {
            attn_agg_move_k<256><<<cdiv(N_NODES, 4), 256, 0, stream>>>(
                a_s, a_d, srcv, csr, offs, tin[l], thagg,
                cprev[l], bd, cout[l], tnext[l], ldn[l],
                xAv[l], offAv[l], xBv[l], offBv[l]);
        }

        if (l < 3) {
            int klen = K6 / KS;
            gemm_split_k<<<dim3(Cpad / 128, MPAD / 128, KS), 256, 0, stream>>>(
                thagg, VtL[l], partb, K6, klen, Cpad);
            reduce_feat_k<<<cdiv(MPAD * (Cpad / 2), 256), 256, 0, stream>>>(
                partb, tnext[l], KS, Cpad, ldn[l], foff[l], C);
        }
    }
}

// Round 11
// 331.078 us; speedup vs baseline: 1.6313x; 1.0509x over previous
//
#include <hip/hip_runtime.h>
#include <hip/hip_bf16.h>

#define N_NODES 10000
#define N_EDGES 70000
#define HEADS 6
#define MPAD 10112            // ceil(10000/128)*128
#define SELU_SCALE 1.0507009873554805f
#define SELU_ALPHA  1.6732632423543772f
#define NEG_SLOPE 0.2f

typedef __attribute__((ext_vector_type(8))) __bf16 bf16x8;
typedef __attribute__((ext_vector_type(4))) float f32x4;

__device__ __forceinline__ float selu_f(float x) {
    return x > 0.f ? SELU_SCALE * x : SELU_SCALE * SELU_ALPHA * (__expf(x) - 1.f);
}
__device__ __forceinline__ unsigned short f2bf(float f) {
    __hip_bfloat16 h = __float2bfloat16(f);
    return __builtin_bit_cast(unsigned short, h);
}
__device__ __forceinline__ float bf2f(unsigned short u) {
    unsigned int x = ((unsigned int)u) << 16;
    return __builtin_bit_cast(float, x);
}

// ---------------- CSR build ----------------
__global__ void count_edges_k(const int* __restrict__ dstv, int* __restrict__ counts) {
    int e = blockIdx.x * blockDim.x + threadIdx.x;
    if (e < N_EDGES) atomicAdd(&counts[dstv[e]], 1);
}

__global__ __launch_bounds__(1024) void scan_k(const int* __restrict__ counts, int* __restrict__ offs) {
    __shared__ int part[1024];
    int tid = threadIdx.x;
    const int per = (N_NODES + 1023) / 1024;  // 10
    int start = tid * per;
    int s = 0;
    for (int i = 0; i < per; ++i) { int idx = start + i; if (idx < N_NODES) s += counts[idx]; }
    part[tid] = s;
    __syncthreads();
    for (int off = 1; off < 1024; off <<= 1) {
        int v = (tid >= off) ? part[tid - off] : 0;
        __syncthreads();
        part[tid] += v;
        __syncthreads();
    }
    int run = part[tid] - s;
    for (int i = 0; i < per; ++i) {
        int idx = start + i;
        if (idx < N_NODES) { offs[idx] = run; run += counts[idx]; }
    }
    if (tid == 0) offs[N_NODES] = part[1023];
}

__global__ void fill_csr_k(const int* __restrict__ dstv, const int* __restrict__ offs,
                           int* __restrict__ cursor, int* __restrict__ csr) {
    int e = blockIdx.x * blockDim.x + threadIdx.x;
    if (e < N_EDGES) {
        int d = dstv[e];
        int pos = atomicAdd(&cursor[d], 1);
        csr[offs[d] + pos] = e;
    }
}

// ---------------- prep: coords0 + t1 = [x, y, selu(data@W_lin+b)] ----------------
__global__ __launch_bounds__(256) void prep_k(const float* __restrict__ data,
                                              const float* __restrict__ W,
                                              const float* __restrict__ b,
                                              float* __restrict__ coords0,
                                              unsigned short* __restrict__ t1) {
    int idx = blockIdx.x * blockDim.x + threadIdx.x;
    if (idx >= N_NODES * 256) return;
    int n = idx >> 8, c = idx & 255;
    if (c < 2) {
        float v = data[n * 10 + c];
        t1[(size_t)n * 256 + c] = f2bf(v);
        if (c == 0) {
            coords0[2 * n] = data[n * 10];
            coords0[2 * n + 1] = data[n * 10 + 1];
        }
    } else {
        int cc = c - 2;
        float acc = b[cc];
        const float* dr = data + (size_t)n * 10;
#pragma unroll
        for (int k = 0; k < 10; ++k) acc += dr[k] * W[k * 254 + cc];
        t1[(size_t)n * 256 + c] = f2bf(selu_f(acc));
    }
}

// ---------------- fold all 4 layers in one launch: one wave per (layer,k,h) ----------------
__global__ __launch_bounds__(64) void fold_all_k(
    const float* __restrict__ W0, const float* __restrict__ s0v, const float* __restrict__ d0v,
    const float* __restrict__ W1, const float* __restrict__ s1v, const float* __restrict__ d1v,
    const float* __restrict__ W2, const float* __restrict__ s2v, const float* __restrict__ d2v,
    const float* __restrict__ W3, const float* __restrict__ s3v, const float* __restrict__ d3v,
    float* __restrict__ wsf0, float* __restrict__ wdf0,
    float* __restrict__ wsf1, float* __restrict__ wdf1,
    float* __restrict__ wsf2, float* __restrict__ wdf2,
    float* __restrict__ wsf3, float* __restrict__ wdf3) {
    int bid = blockIdx.x;
    const float* W; const float* sv; const float* dv; float* ws; float* wd;
    int K, C, pair;
    if (bid < 1536)      { W = W0; sv = s0v; dv = d0v; ws = wsf0; wd = wdf0; K = 256; C = 508; pair = bid; }
    else if (bid < 4608) { W = W1; sv = s1v; dv = d1v; ws = wsf1; wd = wdf1; K = 512; C = 250; pair = bid - 1536; }
    else if (bid < 6144) { W = W2; sv = s2v; dv = d2v; ws = wsf2; wd = wdf2; K = 256; C = 120; pair = bid - 4608; }
    else                 { W = W3; sv = s3v; dv = d3v; ws = wsf3; wd = wdf3; K = 128; C = 20;  pair = bid - 6144; }
    int k = pair / HEADS, h = pair % HEADS;
    int lane = threadIdx.x;
    const float* wr = W + (size_t)k * (HEADS * C) + h * C;
    const float* sr = sv + h * C;
    const float* dr = dv + h * C;
    float s = 0.f, d = 0.f;
    for (int c = lane; c < C; c += 64) {
        float w = wr[c];
        s += w * sr[c];
        d += w * dr[c];
    }
#pragma unroll
    for (int off = 32; off > 0; off >>= 1) {
        s += __shfl_xor(s, off);
        d += __shfl_xor(d, off);
    }
    if (lane == 0) { ws[pair] = s; wd[pair] = d; }
}

// ---------------- Vt build for all 3 GEMM layers in one launch ----------------
__global__ __launch_bounds__(256) void convv_all_k(
    const float* __restrict__ W0, unsigned short* __restrict__ Vt0,
    const float* __restrict__ W1, unsigned short* __restrict__ Vt1,
    const float* __restrict__ W2, unsigned short* __restrict__ Vt2) {
    __shared__ float tile[64][65];
    int bid = blockIdx.x;
    const float* W; unsigned short* Vt; int K, C, K6, bid2, ktiles;
    if (bid < 192)      { W = W0; Vt = Vt0; K = 256; C = 508; K6 = 1536; bid2 = bid;       ktiles = 24; }
    else if (bid < 384) { W = W1; Vt = Vt1; K = 512; C = 250; K6 = 3072; bid2 = bid - 192; ktiles = 48; }
    else                { W = W2; Vt = Vt2; K = 256; C = 120; K6 = 1536; bid2 = bid - 384; ktiles = 24; }
    int kb = bid2 % ktiles, cb = bid2 / ktiles;
    const int tx = threadIdx.x;
    const int ty = threadIdx.y;
    const int k0 = kb * 64;
    const int c0 = cb * 64;
    for (int i = ty; i < 64; i += 4) {
        int kk = k0 + i;
        int h = kk / K, k = kk - h * K;
        int c = c0 + tx;
        tile[i][tx] = (c < C) ? W[(size_t)k * (HEADS * C) + h * C + c] : 0.f;
    }
    __syncthreads();
    for (int i = ty; i < 64; i += 4) {
        int c = c0 + i;
        Vt[(size_t)c * K6 + k0 + tx] = f2bf(tile[tx][i]);
    }
}

// ---------------- split-K MFMA GEMM: partial[kz][m][n] (bf16, no epilogue) ----------------
__global__ __launch_bounds__(256) void gemm_split_k(
    const unsigned short* __restrict__ A,
    const unsigned short* __restrict__ Bt,
    unsigned short* __restrict__ part,
    int Kpitch, int klen, int Npad) {
    __shared__ unsigned short lds[16384];
    const int tid = threadIdx.x;
    const int lane = tid & 63, wid = tid >> 6;
    const int wm = wid >> 1, wn = wid & 1;
    const int m0 = blockIdx.y * 128;
    const int n0 = blockIdx.x * 128;
    const int kz = blockIdx.z;
    const int kbeg = kz * klen;

    f32x4 acc[4][4] = {};

    const unsigned short* gsrc[8];
    unsigned ldsoff[8];
#pragma unroll
    for (int i = 0; i < 8; ++i) {
        const int half = i >> 2;
        const int slot = (i & 3) * 256 + tid;
        const int r = slot >> 3;
        const int c16 = slot & 7;
        const int ksl = c16 ^ (r & 7);
        gsrc[i] = (half ? (Bt + (size_t)(n0 + r) * Kpitch) : (A + (size_t)(m0 + r) * Kpitch)) + ksl * 8;
        ldsoff[i] = (unsigned)(half * 8192 + ((i & 3) * 256 + wid * 64) * 8);
    }

    for (int kt = kbeg; kt < kbeg + klen; kt += 64) {
#pragma unroll
        for (int i = 0; i < 8; ++i) {
            __builtin_amdgcn_global_load_lds(
                (const __attribute__((address_space(1))) unsigned int*)(gsrc[i] + kt),
                (__attribute__((address_space(3))) unsigned int*)(&lds[ldsoff[i]]),
                16, 0, 0);
        }
        __syncthreads();
#pragma unroll
        for (int kc = 0; kc < 2; ++kc) {
            const int xo = (((kc * 4 + (lane >> 4)) ^ (lane & 7)) << 4);
            bf16x8 aop[4], bop[4];
#pragma unroll
            for (int f = 0; f < 4; ++f) {
                const int rA = wm * 64 + f * 16 + (lane & 15);
                bop[f] = *(const bf16x8*)((const char*)lds + rA * 128 + xo);
                const int rB = wn * 64 + f * 16 + (lane & 15);
                aop[f] = *(const bf16x8*)((const char*)lds + 16384 * 1 + rB * 128 + xo);
            }
#pragma unroll
            for (int fm = 0; fm < 4; ++fm)
#pragma unroll
                for (int fn = 0; fn < 4; ++fn)
                    acc[fm][fn] = __builtin_amdgcn_mfma_f32_16x16x32_bf16(
                        aop[fn], bop[fm], acc[fm][fn], 0, 0, 0);
        }
        __syncthreads();
    }

    unsigned short* pbase = part + (size_t)kz * MPAD * Npad;
    const int mrow = m0 + wm * 64 + (lane & 15);
    const int ncol = n0 + wn * 64 + ((lane >> 4) * 4);
#pragma unroll
    for (int fm = 0; fm < 4; ++fm) {
#pragma unroll
        for (int fn = 0; fn < 4; ++fn) {
            f32x4 v = acc[fm][fn];
            unsigned int u0 = (unsigned int)f2bf(v.x) | ((unsigned int)f2bf(v.y) << 16);
            unsigned int u1 = (unsigned int)f2bf(v.z) | ((unsigned int)f2bf(v.w) << 16);
            uint2 pk = make_uint2(u0, u1);
            *(uint2*)&pbase[(size_t)(mrow + fm * 16) * Npad + ncol + fn * 16] = pk;
        }
    }
}

// ---------------- proj: one wave per node (layer 1 only) ----------------
__global__ __launch_bounds__(256) void proj2_k(const unsigned short* __restrict__ t,
                                               const float* __restrict__ wsf,
                                               const float* __restrict__ wdf,
                                               float* __restrict__ a_s,
                                               float* __restrict__ a_d, int K) {
    const int wv = threadIdx.x >> 6;
    const int lane = threadIdx.x & 63;
    const int n = blockIdx.x * 4 + wv;
    if (n >= N_NODES) return;
    const unsigned short* tr = t + (size_t)n * K;
    const int kpl = K >> 6;
    const int k0 = lane * kpl;

    unsigned int buf[4] = {0u, 0u, 0u, 0u};
    if (kpl == 8) {
        uint4 u = *(const uint4*)(tr + k0);
        buf[0] = u.x; buf[1] = u.y; buf[2] = u.z; buf[3] = u.w;
    } else if (kpl == 4) {
        uint2 u = *(const uint2*)(tr + k0);
        buf[0] = u.x; buf[1] = u.y;
    } else {
        buf[0] = *(const unsigned int*)(tr + k0);
    }

    float s[HEADS] = {}, d[HEADS] = {};
#pragma unroll
    for (int j = 0; j < 8; ++j) {
        if (j >= kpl) break;
        unsigned int w = buf[j >> 1];
        unsigned short u = (j & 1) ? (unsigned short)(w >> 16) : (unsigned short)(w & 0xffff);
        float v = bf2f(u);
        const float* ws = wsf + (size_t)(k0 + j) * HEADS;
        const float* wd = wdf + (size_t)(k0 + j) * HEADS;
#pragma unroll
        for (int h = 0; h < HEADS; ++h) {
            s[h] += v * ws[h];
            d[h] += v * wd[h];
        }
    }
#pragma unroll
    for (int off = 32; off > 0; off >>= 1) {
#pragma unroll
        for (int h = 0; h < HEADS; ++h) {
            s[h] += __shfl_xor(s[h], off);
            d[h] += __shfl_xor(d[h], off);
        }
    }
    if (lane == 0) {
#pragma unroll
        for (int h = 0; h < HEADS; ++h) {
            a_s[n * HEADS + h] = s[h];
            a_d[n * HEADS + h] = d[h];
        }
    }
}

// ---------------- fused reduce-partials + selu + next-layer proj: one wave per node --------
// KN = next-layer row width (ld). Reads coord cols (written by attn), reduces KS partials
// for feat cols, writes them, and computes next-layer a_s/a_d from register values.
template<int KN>
__global__ __launch_bounds__(256) void reduceproj_k(
    const unsigned short* __restrict__ part, int KS, int Npad, int off,
    unsigned short* __restrict__ tnext,
    const float* __restrict__ wsf, const float* __restrict__ wdf,
    float* __restrict__ a_s, float* __restrict__ a_d) {
    const int wid = threadIdx.x >> 6, lane = threadIdx.x & 63;
    const int n = blockIdx.x * 4 + wid;
    if (n >= N_NODES) return;
    constexpr int KPL = KN / 64;
    const int c0 = lane * KPL;
    unsigned short* row = tnext + (size_t)n * KN;

    float vals[KPL];
#pragma unroll
    for (int q = 0; q < KPL; ++q) {
        int c = c0 + q;
        if (c < off) {
            vals[q] = bf2f(row[c]);
        } else {
            int cp = c - off;
            float sum = 0.f;
            for (int kz = 0; kz < KS; ++kz)
                sum += bf2f(part[(size_t)kz * MPAD * Npad + (size_t)n * Npad + cp]);
            float o = selu_f(sum * (1.f / 6.f));
            vals[q] = o;
            row[c] = f2bf(o);
        }
    }

    float s[HEADS] = {}, d[HEADS] = {};
#pragma unroll
    for (int q = 0; q < KPL; ++q) {
        int c = c0 + q;
        float v = vals[q];
        const float* ws = wsf + (size_t)c * HEADS;
        const float* wd = wdf + (size_t)c * HEADS;
#pragma unroll
        for (int h = 0; h < HEADS; ++h) {
            s[h] += v * ws[h];
            d[h] += v * wd[h];
        }
    }
#pragma unroll
    for (int off2 = 32; off2 > 0; off2 >>= 1) {
#pragma unroll
        for (int h = 0; h < HEADS; ++h) {
            s[h] += __shfl_xor(s[h], off2);
            d[h] += __shfl_xor(d[h], off2);
        }
    }
    if (lane == 0) {
#pragma unroll
        for (int h = 0; h < HEADS; ++h) {
            a_s[n * HEADS + h] = s[h];
            a_d[n * HEADS + h] = d[h];
        }
    }
}

// ---------------- fused softmax + aggregate + move_coords: ONE WAVE PER NODE ---------------
// Alpha computed ONCE per edge by its owner lane (myal), broadcast via __shfl in the j-loop.
template<int KT>
__global__ __launch_bounds__(256) void attn_agg_move_k(
    const float* __restrict__ a_s, const float* __restrict__ a_d,
    const int* __restrict__ srcv, const int* __restrict__ csr,
    const int* __restrict__ offs,
    const unsigned short* __restrict__ t_in, unsigned short* __restrict__ thagg,
    const float* __restrict__ cprev, const int* __restrict__ bd,
    float* __restrict__ cout, unsigned short* __restrict__ tnext, int ld,
    const float* __restrict__ xA, int offA,
    const float* __restrict__ xB, int offB) {
    const int wid = threadIdx.x >> 6, lane = threadIdx.x & 63;
    const int n = blockIdx.x * 4 + wid;
    if (n >= N_NODES) return;
    const int r0 = offs[n], r1 = offs[n + 1];

    float ad[HEADS], mm[HEADS], ss[HEADS];
#pragma unroll
    for (int h = 0; h < HEADS; ++h) {
        ad[h] = a_d[n * HEADS + h];          // same addr across lanes: broadcast
        mm[h] = -1e30f; ss[h] = 0.f;
    }

    // ---- phase A: per-head online softmax stats, edges striped by lane ----
    for (int base = r0; base < r1; base += 64) {
        int i = base + lane;
        if (i < r1) {
            int src = srcv[csr[i]];
#pragma unroll
            for (int h = 0; h < HEADS; ++h) {
                float v = a_s[src * HEADS + h] + ad[h];
                v = v > 0.f ? v : NEG_SLOPE * v;
                float nm = fmaxf(mm[h], v);
                ss[h] = ss[h] * __expf(mm[h] - nm) + __expf(v - nm);
                mm[h] = nm;
            }
        }
    }
#pragma unroll
    for (int off = 32; off > 0; off >>= 1) {
#pragma unroll
        for (int h = 0; h < HEADS; ++h) {
            float mo = __shfl_xor(mm[h], off);
            float so = __shfl_xor(ss[h], off);
            float nm = fmaxf(mm[h], mo);
            ss[h] = ss[h] * __expf(mm[h] - nm) + so * __expf(mo - nm);
            mm[h] = nm;
        }
    }
    float rd[HEADS];
#pragma unroll
    for (int h = 0; h < HEADS; ++h) rd[h] = ss[h] > 0.f ? 1.f / ss[h] : 0.f;

    // ---- phase B: alpha once per edge (owner lane), broadcast via shfl ----
    constexpr int KPL = (KT > 0) ? (KT / 64) : 1;
    float acc[HEADS][KPL] = {};
    float cx = 0.f, cy = 0.f;
    for (int base = r0; base < r1; base += 64) {
        int i = base + lane;
        bool ok = i < r1;
        int mysrc = ok ? srcv[csr[i]] : 0;
        float myal[HEADS];
#pragma unroll
        for (int h = 0; h < HEADS; ++h) myal[h] = 0.f;
        if (ok) {
            float am = 0.f;
#pragma unroll
            for (int h = 0; h < HEADS; ++h) {
                float v = a_s[mysrc * HEADS + h] + ad[h];
                v = v > 0.f ? v : NEG_SLOPE * v;
                float a = __expf(v - mm[h]) * rd[h];
                myal[h] = a;
                am += a;
            }
            am *= (1.f / 6.f);
            cx += am * cprev[2 * mysrc];
            cy += am * cprev[2 * mysrc + 1];
        }
        if constexpr (KT > 0) {
            int cnt = min(64, r1 - base);
            for (int j = 0; j < cnt; ++j) {
                int src = __shfl(mysrc, j);
                float al[HEADS];
#pragma unroll
                for (int h = 0; h < HEADS; ++h) al[h] = __shfl(myal[h], j);
                if constexpr (KT == 512) {
                    uint4 u = *(const uint4*)(t_in + (size_t)src * 512 + lane * 8);
                    float tv[8];
                    tv[0] = bf2f((unsigned short)(u.x & 0xffff)); tv[1] = bf2f((unsigned short)(u.x >> 16));
                    tv[2] = bf2f((unsigned short)(u.y & 0xffff)); tv[3] = bf2f((unsigned short)(u.y >> 16));
                    tv[4] = bf2f((unsigned short)(u.z & 0xffff)); tv[5] = bf2f((unsigned short)(u.z >> 16));
                    tv[6] = bf2f((unsigned short)(u.w & 0xffff)); tv[7] = bf2f((unsigned short)(u.w >> 16));
#pragma unroll
                    for (int h = 0; h < HEADS; ++h)
#pragma unroll
                        for (int q = 0; q < 8; ++q) acc[h][q] += al[h] * tv[q];
                } else {
                    uint2 u = *(const uint2*)(t_in + (size_t)src * 256 + lane * 4);
                    float tv[4];
                    tv[0] = bf2f((unsigned short)(u.x & 0xffff)); tv[1] = bf2f((unsigned short)(u.x >> 16));
                    tv[2] = bf2f((unsigned short)(u.y & 0xffff)); tv[3] = bf2f((unsigned short)(u.y >> 16));
#pragma unroll
                    for (int h = 0; h < HEADS; ++h)
#pragma unroll
                        for (int q = 0; q < 4; ++q) acc[h][q] += al[h] * tv[q];
                }
            }
        }
    }

    // ---- phase C: writes ----
    if constexpr (KT == 512) {
#pragma unroll
        for (int h = 0; h < HEADS; ++h) {
            uint4 pk;
            pk.x = (unsigned int)f2bf(acc[h][0]) | ((unsigned int)f2bf(acc[h][1]) << 16);
            pk.y = (unsigned int)f2bf(acc[h][2]) | ((unsigned int)f2bf(acc[h][3]) << 16);
            pk.z = (unsigned int)f2bf(acc[h][4]) | ((unsigned int)f2bf(acc[h][5]) << 16);
            pk.w = (unsigned int)f2bf(acc[h][6]) | ((unsigned int)f2bf(acc[h][7]) << 16);
            *(uint4*)(thagg + (size_t)n * 3072 + h * 512 + lane * 8) = pk;
        }
    } else if constexpr (KT == 256) {
#pragma unroll
        for (int h = 0; h < HEADS; ++h) {
            uint2 pk;
            pk.x = (unsigned int)f2bf(acc[h][0]) | ((unsigned int)f2bf(acc[h][1]) << 16);
            pk.y = (unsigned int)f2bf(acc[h][2]) | ((unsigned int)f2bf(acc[h][3]) << 16);
            *(uint2*)(thagg + (size_t)n * 1536 + h * 256 + lane * 4) = pk;
        }
    }
#pragma unroll
    for (int off = 32; off > 0; off >>= 1) {
        cx += __shfl_xor(cx, off);
        cy += __shfl_xor(cy, off);
    }
    if (lane == 0) {
        float px = cprev[2 * n], py = cprev[2 * n + 1];
        float ocx, ocy;
        if (bd[n] != 0) { ocx = px; ocy = py; }
        else { ocx = cx; ocy = cy; }
        cout[2 * n] = ocx; cout[2 * n + 1] = ocy;
        if (tnext) {
            unsigned short* row = tnext + (size_t)n * ld;
            row[0] = f2bf(ocx); row[1] = f2bf(ocy);
            row[2] = f2bf(px);  row[3] = f2bf(py);
            if (xA) { row[offA] = f2bf(xA[2 * n]); row[offA + 1] = f2bf(xA[2 * n + 1]); }
            if (xB) { row[offB] = f2bf(xB[2 * n]); row[offB + 1] = f2bf(xB[2 * n + 1]); }
        }
    }
}

static inline int cdiv(int a, int b) { return (a + b - 1) / b; }

extern "C" void kernel_launch(void* const* d_in, const int* in_sizes, int n_in,
                              void* d_out, int out_size, void* d_ws, size_t ws_size,
                              hipStream_t stream) {
    const float* data = (const float*)d_in[0];
    const int* eidx = (const int*)d_in[1];
    const int* bd = (const int*)d_in[2];
    const float* W_lin = (const float*)d_in[4];
    const float* b_lin = (const float*)d_in[5];
    const float* Wl[4]  = {(const float*)d_in[6],  (const float*)d_in[9],
                           (const float*)d_in[12], (const float*)d_in[15]};
    const float* Asrc[4] = {(const float*)d_in[7],  (const float*)d_in[10],
                            (const float*)d_in[13], (const float*)d_in[16]};
    const float* Adst[4] = {(const float*)d_in[8],  (const float*)d_in[11],
                            (const float*)d_in[14], (const float*)d_in[17]};
    const int Kd[4] = {256, 512, 256, 128};
    const int Cpadd[4] = {512, 256, 128, 0};
    const int KSd[4] = {2, 4, 4, 0};

    const int* srcv = eidx;
    const int* dstv = eidx + N_EDGES;

    char* p = (char*)d_ws;
    auto alloc = [&](size_t bytes) -> void* {
        void* r = (void*)p;
        p += (bytes + 255) & ~(size_t)255;
        return r;
    };
    unsigned short* tb1 = (unsigned short*)alloc((size_t)MPAD * 256 * 2);
    unsigned short* tb2 = (unsigned short*)alloc((size_t)MPAD * 512 * 2);
    unsigned short* tb3 = (unsigned short*)alloc((size_t)MPAD * 256 * 2);
    unsigned short* tb4 = (unsigned short*)alloc((size_t)MPAD * 128 * 2);
    unsigned short* thagg = (unsigned short*)alloc((size_t)MPAD * 3072 * 2);
    unsigned short* VtL[3];
    VtL[0] = (unsigned short*)alloc((size_t)512 * 1536 * 2);
    VtL[1] = (unsigned short*)alloc((size_t)256 * 3072 * 2);
    VtL[2] = (unsigned short*)alloc((size_t)128 * 1536 * 2);
    unsigned short* partb = (unsigned short*)alloc((size_t)8 * MPAD * 256 * 2);
    float* coords0 = (float*)alloc((size_t)N_NODES * 2 * 4);
    float* c1 = (float*)alloc((size_t)N_NODES * 2 * 4);
    float* c2 = (float*)alloc((size_t)N_NODES * 2 * 4);
    float* c3 = (float*)alloc((size_t)N_NODES * 2 * 4);
    float* a_s = (float*)alloc((size_t)N_NODES * HEADS * 4);
    float* a_d = (float*)alloc((size_t)N_NODES * HEADS * 4);
    float* wsfL[4]; float* wdfL[4];
    wsfL[0] = (float*)alloc(1536 * 4); wdfL[0] = (float*)alloc(1536 * 4);
    wsfL[1] = (float*)alloc(3072 * 4); wdfL[1] = (float*)alloc(3072 * 4);
    wsfL[2] = (float*)alloc(1536 * 4); wdfL[2] = (float*)alloc(1536 * 4);
    wsfL[3] = (float*)alloc(768 * 4);  wdfL[3] = (float*)alloc(768 * 4);
    int* counts = (int*)alloc((size_t)N_NODES * 4);   // counts+cursor adjacent: one memset
    int* cursor = (int*)alloc((size_t)N_NODES * 4);
    int* offs = (int*)alloc((size_t)(N_NODES + 1) * 4);
    int* csr = (int*)alloc((size_t)N_EDGES * 4);

    hipMemsetAsync(counts, 0, (size_t)((char*)offs - (char*)counts), stream);
    count_edges_k<<<cdiv(N_EDGES, 256), 256, 0, stream>>>(dstv, counts);
    scan_k<<<1, 1024, 0, stream>>>(counts, offs);
    fill_csr_k<<<cdiv(N_EDGES, 256), 256, 0, stream>>>(dstv, offs, cursor, csr);

    prep_k<<<cdiv(N_NODES * 256, 256), 256, 0, stream>>>(data, W_lin, b_lin, coords0, tb1);
    fold_all_k<<<6912, 64, 0, stream>>>(
        Wl[0], Asrc[0], Adst[0], Wl[1], Asrc[1], Adst[1],
        Wl[2], Asrc[2], Adst[2], Wl[3], Asrc[3], Adst[3],
        wsfL[0], wdfL[0], wsfL[1], wdfL[1], wsfL[2], wdfL[2], wsfL[3], wdfL[3]);
    convv_all_k<<<432, dim3(64, 4), 0, stream>>>(Wl[0], VtL[0], Wl[1], VtL[1], Wl[2], VtL[2]);

    unsigned short* tin[4]   = {tb1, tb2, tb3, tb4};
    unsigned short* tnext[4] = {tb2, tb3, tb4, nullptr};
    int ldn[4]  = {512, 256, 128, 0};
    int foff[4] = {4, 6, 8, 0};
    float* cprev[4] = {coords0, c1, c2, c3};
    float* cout[4]  = {c1, c2, c3, (float*)d_out};
    const float* xAv[4] = {nullptr, coords0, c1, nullptr};
    int offAv[4] = {0, 4, 4, 0};
    const float* xBv[4] = {nullptr, nullptr, coords0, nullptr};
    int offBv[4] = {0, 0, 6, 0};

    // layer-1 proj (standalone); later layers get a_s/a_d from reduceproj
    proj2_k<<<cdiv(N_NODES, 4), 256, 0, stream>>>(tb1, wsfL[0], wdfL[0], a_s, a_d, 256);

    for (int l = 0; l < 4; ++l) {
        int K = Kd[l], Cpad = Cpadd[l], KS = KSd[l];
        int K6 = K * HEADS;

        if (l == 3) {
            attn_agg_move_k<0><<<cdiv(N_NODES, 4), 256, 0, stream>>>(
                a_s, a_d, srcv, csr, offs, tin[l], nullptr,
                cprev[l], bd, cout[l], tnext[l], ldn[l],
                xAv[l], offAv[l], xBv[l], offBv[l]);
        } else if (K == 512) {
            attn_agg_move_k<512><<<cdiv(N_NODES, 4), 256, 0, stream>>>(
                a_s, a_d, srcv, csr, offs, tin[l], thagg,
                cprev[l], bd, cout[l], tnext[l], ldn[l],
                xAv[l], offAv[l], xBv[l], offBv[l]);
        } else {
            attn_agg_move_k<256><<<cdiv(N_NODES, 4), 256, 0, stream>>>(
                a_s, a_d, srcv, csr, offs, tin[l], thagg,
                cprev[l], bd, cout[l], tnext[l], ldn[l],
                xAv[l], offAv[l], xBv[l], offBv[l]);
        }

        if (l < 3) {
            int klen = K6 / KS;
            gemm_split_k<<<dim3(Cpad / 128, MPAD / 128, KS), 256, 0, stream>>>(
                thagg, VtL[l], partb, K6, klen, Cpad);
            // fused: reduce partials -> selu -> write tnext feats -> next-layer proj
            if (ldn[l] == 512) {
                reduceproj_k<512><<<cdiv(N_NODES, 4), 256, 0, stream>>>(
                    partb, KS, Cpad, foff[l], tnext[l], wsfL[l + 1], wdfL[l + 1], a_s, a_d);
            } else if (ldn[l] == 256) {
                reduceproj_k<256><<<cdiv(N_NODES, 4), 256, 0, stream>>>(
                    partb, KS, Cpad, foff[l], tnext[l], wsfL[l + 1], wdfL[l + 1], a_s, a_d);
            } else {
                reduceproj_k<128><<<cdiv(N_NODES, 4), 256, 0, stream>>>(
                    partb, KS, Cpad, foff[l], tnext[l], wsfL[l + 1], wdfL[l + 1], a_s, a_d);
            }
        }
    }
}